// Round 1
// baseline (984.330 us; speedup 1.0000x reference)
//
#include <hip/hip_runtime.h>
#include <math.h>

// Problem constants
#define BB 2
#define SS 2048
#define DD 512
#define HH 1024
#define MMETA 64
#define KCONV 4
#define NHH 8
#define DHH 64
#define WINN 256
#define TT (MMETA + SS)     // 2112
#define BT (BB * TT)        // 4224

// ---------------------------------------------------------------------------
// Kernel 1: build xm = concat(meta_memory broadcast, x) -> [BT, D]
// ---------------------------------------------------------------------------
__global__ __launch_bounds__(256) void build_xm_k(
    const float* __restrict__ x, const float* __restrict__ meta,
    float* __restrict__ xm)
{
    int idx = blockIdx.x * 256 + threadIdx.x;      // float4 index
    const int c4_per_row = DD / 4;                  // 128
    int row = idx / c4_per_row;
    int c4  = idx % c4_per_row;
    if (row >= BT) return;
    int b = row / TT, t = row % TT;
    float4 v;
    if (t < MMETA) {
        v = ((const float4*)(meta + (size_t)t * DD))[c4];
    } else {
        v = ((const float4*)(x + ((size_t)b * SS + (t - MMETA)) * DD))[c4];
    }
    ((float4*)xm)[idx] = v;
}

// ---------------------------------------------------------------------------
// Kernel 2: generic tiled fp32 GEMM  C = epi(A @ W + bias [, res])
//   A: [R, Kd] row-major, W: [Kd, N] row-major, C: [R, N]
//   EPI: 0 = bias only, 1 = silu(acc+bias), 2 = res + silu(acc+bias)
//   DROPMETA: write only rows with t >= MMETA to out[(b*S + t-M)*N + col]
//   BM=BN=64, BK=16, 256 threads, 4x4 per thread
// ---------------------------------------------------------------------------
template<int EPI, bool DROPMETA>
__global__ __launch_bounds__(256) void gemm_k(
    const float* __restrict__ A, const float* __restrict__ W,
    const float* __restrict__ bias, const float* __restrict__ res,
    float* __restrict__ C, int Kd, int N)
{
    __shared__ float As[16][64];   // As[k][m]
    __shared__ float Bs[16][64];   // Bs[k][n]

    const int tid = threadIdx.x;
    const int tx = tid & 15;       // 0..15 -> col group
    const int ty = tid >> 4;       // 0..15 -> row group
    const int row0 = blockIdx.x * 64;
    const int n0   = blockIdx.y * 64;

    const int ar  = tid >> 2;      // 0..63  A tile row
    const int ac4 = tid & 3;       // 0..3   A tile col (x4)
    const int br  = tid >> 4;      // 0..15  B tile row
    const int bc  = (tid & 15) * 4;

    float acc[4][4] = {};

    for (int k0 = 0; k0 < Kd; k0 += 16) {
        float4 av = *(const float4*)(A + (size_t)(row0 + ar) * Kd + k0 + ac4 * 4);
        float4 bv = *(const float4*)(W + (size_t)(k0 + br) * N + n0 + bc);
        __syncthreads();
        As[ac4 * 4 + 0][ar] = av.x;
        As[ac4 * 4 + 1][ar] = av.y;
        As[ac4 * 4 + 2][ar] = av.z;
        As[ac4 * 4 + 3][ar] = av.w;
        *(float4*)&Bs[br][bc] = bv;
        __syncthreads();
        #pragma unroll
        for (int kk = 0; kk < 16; ++kk) {
            float a[4], b[4];
            #pragma unroll
            for (int i = 0; i < 4; ++i) a[i] = As[kk][ty * 4 + i];
            #pragma unroll
            for (int j = 0; j < 4; ++j) b[j] = Bs[kk][tx * 4 + j];
            #pragma unroll
            for (int i = 0; i < 4; ++i)
                #pragma unroll
                for (int j = 0; j < 4; ++j)
                    acc[i][j] += a[i] * b[j];
        }
    }

    #pragma unroll
    for (int i = 0; i < 4; ++i) {
        int row = row0 + ty * 4 + i;
        #pragma unroll
        for (int j = 0; j < 4; ++j) {
            int col = n0 + tx * 4 + j;
            float v = acc[i][j] + bias[col];
            if (EPI >= 1) v = v / (1.f + __expf(-v));      // silu
            if (EPI == 2) v += res[(size_t)row * N + col]; // residual
            if (DROPMETA) {
                int b = row / TT, t = row % TT;
                if (t >= MMETA)
                    C[((size_t)b * SS + (t - MMETA)) * N + col] = v;
            } else {
                C[(size_t)row * N + col] = v;
            }
        }
    }
}

// ---------------------------------------------------------------------------
// Kernel 3: causal depthwise conv (K=4) + L2 normalize each row
//   qn[b,t,d] = normalize( sum_k qlin[b, t-3+k, d] * convw[k,d] )
//   one block (256 thr) per row; D=512 -> 2 elems/thread
// ---------------------------------------------------------------------------
__global__ __launch_bounds__(256) void conv_norm_k(
    const float* __restrict__ qlin, const float* __restrict__ convw,
    float* __restrict__ qn)
{
    const int row = blockIdx.x;          // 0..BT-1
    const int b = row / TT, t = row % TT;
    const int tid = threadIdx.x;

    float vals[2];
    float ss = 0.f;
    #pragma unroll
    for (int e = 0; e < 2; ++e) {
        int d = tid + e * 256;
        float acc = 0.f;
        #pragma unroll
        for (int k = 0; k < KCONV; ++k) {
            int tt = t - (KCONV - 1) + k;
            if (tt >= 0)
                acc += qlin[((size_t)b * TT + tt) * DD + d] * convw[k * DD + d];
        }
        vals[e] = acc;
        ss += acc * acc;
    }
    // block reduction of ss (4 waves)
    #pragma unroll
    for (int off = 32; off > 0; off >>= 1)
        ss += __shfl_xor(ss, off);
    __shared__ float red[4];
    if ((tid & 63) == 0) red[tid >> 6] = ss;
    __syncthreads();
    float total = red[0] + red[1] + red[2] + red[3];
    float inv = 1.f / fmaxf(sqrtf(total), 1e-12f);
    #pragma unroll
    for (int e = 0; e < 2; ++e) {
        int d = tid + e * 256;
        qn[(size_t)row * DD + d] = vals[e] * inv;
    }
}

// ---------------------------------------------------------------------------
// Kernel 4: sliding-window causal attention, one wave per (b, h, query)
//   scores over window [max(0,i-255), i], softmax, PV, write o
// ---------------------------------------------------------------------------
__global__ __launch_bounds__(64) void swa_attn_k(
    const float* __restrict__ qb, const float* __restrict__ kb,
    const float* __restrict__ vb, float* __restrict__ ob)
{
    const int i = blockIdx.x;        // query pos 0..T-1
    const int h = blockIdx.y;
    const int b = blockIdx.z;
    const int lane = threadIdx.x;    // 0..63

    __shared__ float qs[DHH];
    __shared__ float ps[WINN];

    const size_t hoff = (size_t)h * DHH;
    // load q row into LDS
    qs[lane] = qb[((size_t)b * TT + i) * DD + hoff + lane];
    __syncthreads();

    const int jstart = (i - WINN + 1 > 0) ? (i - WINN + 1) : 0;
    const int cnt = i - jstart + 1;      // 1..256

    float s[4];
    float m = -1e30f;
    const float4* qs4 = (const float4*)qs;
    #pragma unroll
    for (int kk = 0; kk < 4; ++kk) {
        int rel = kk * 64 + lane;
        if (rel < cnt) {
            const float4* kr4 = (const float4*)(kb + ((size_t)b * TT + jstart + rel) * DD + hoff);
            float acc = 0.f;
            #pragma unroll
            for (int d4 = 0; d4 < DHH / 4; ++d4) {
                float4 kv = kr4[d4], qv = qs4[d4];
                acc += qv.x * kv.x + qv.y * kv.y + qv.z * kv.z + qv.w * kv.w;
            }
            s[kk] = acc * 0.125f;        // 1/sqrt(64)
        } else {
            s[kk] = -1e30f;
        }
        m = fmaxf(m, s[kk]);
    }
    #pragma unroll
    for (int off = 32; off > 0; off >>= 1)
        m = fmaxf(m, __shfl_xor(m, off));

    float lsum = 0.f;
    #pragma unroll
    for (int kk = 0; kk < 4; ++kk) {
        int rel = kk * 64 + lane;
        float p = (rel < cnt) ? __expf(s[kk] - m) : 0.f;
        ps[rel] = p;
        lsum += p;
    }
    #pragma unroll
    for (int off = 32; off > 0; off >>= 1)
        lsum += __shfl_xor(lsum, off);
    __syncthreads();

    // PV: lane = output dim d
    float acc = 0.f;
    for (int j = 0; j < cnt; ++j) {
        acc += ps[j] * vb[((size_t)b * TT + jstart + j) * DD + hoff + lane];
    }
    ob[((size_t)b * TT + i) * DD + hoff + lane] = acc / lsum;
}

// ---------------------------------------------------------------------------
// Launch
// ---------------------------------------------------------------------------
extern "C" void kernel_launch(void* const* d_in, const int* in_sizes, int n_in,
                              void* d_out, int out_size, void* d_ws, size_t ws_size,
                              hipStream_t stream)
{
    const float* x        = (const float*)d_in[0];
    const float* meta     = (const float*)d_in[1];
    const float* qp_w     = (const float*)d_in[2];
    const float* qp_b     = (const float*)d_in[3];
    const float* qp_conv  = (const float*)d_in[4];
    const float* w_in     = (const float*)d_in[5];
    const float* b_in     = (const float*)d_in[6];
    const float* w_hid    = (const float*)d_in[7];   // [2,1024,1024]
    const float* b_hid    = (const float*)d_in[8];   // [2,1024]
    const float* w_out    = (const float*)d_in[9];
    const float* b_out    = (const float*)d_in[10];
    const float* wq       = (const float*)d_in[11];
    const float* bq       = (const float*)d_in[12];
    const float* wk       = (const float*)d_in[13];
    const float* bk       = (const float*)d_in[14];
    const float* wv       = (const float*)d_in[15];
    const float* bv       = (const float*)d_in[16];
    const float* wo       = (const float*)d_in[17];
    const float* bo       = (const float*)d_in[18];
    float* out = (float*)d_out;

    // workspace layout (floats)
    float* ws = (float*)d_ws;
    float* xm   = ws;                         // BT*D   (later reused: qn, then ob)
    float* qlin = xm   + (size_t)BT * DD;     // BT*D   (later reused: r)
    float* h_a  = qlin + (size_t)BT * DD;     // BT*HID
    float* h_b  = h_a  + (size_t)BT * HH;     // BT*HID
    float* qb   = h_b  + (size_t)BT * HH;     // BT*D
    float* kb   = qb   + (size_t)BT * DD;     // BT*D
    float* vb   = kb   + (size_t)BT * DD;     // BT*D

    const int R = BT;                          // 4224 rows

    // 1. xm = concat(meta, x)
    {
        int n4 = BT * DD / 4;
        build_xm_k<<<(n4 + 255) / 256, 256, 0, stream>>>(x, meta, xm);
    }
    // 2. qlin = xm @ qp_w + qp_b
    gemm_k<0, false><<<dim3(R / 64, DD / 64), 256, 0, stream>>>(
        xm, qp_w, qp_b, nullptr, qlin, DD, DD);
    // 3. qn(->xm) = l2norm(conv(qlin))
    conv_norm_k<<<BT, 256, 0, stream>>>(qlin, qp_conv, xm);
    // 4. h_a = silu(qn @ w_in + b_in)
    gemm_k<1, false><<<dim3(R / 64, HH / 64), 256, 0, stream>>>(
        xm, w_in, b_in, nullptr, h_a, DD, HH);
    // 5. h_b = h_a + silu(h_a @ w_hid[0] + b_hid[0])
    gemm_k<2, false><<<dim3(R / 64, HH / 64), 256, 0, stream>>>(
        h_a, w_hid, b_hid, h_a, h_b, HH, HH);
    // 6. h_a = h_b + silu(h_b @ w_hid[1] + b_hid[1])
    gemm_k<2, false><<<dim3(R / 64, HH / 64), 256, 0, stream>>>(
        h_b, w_hid + (size_t)HH * HH, b_hid + HH, h_b, h_a, HH, HH);
    // 7. r(->qlin) = silu(h_a @ w_out + b_out)
    gemm_k<1, false><<<dim3(R / 64, DD / 64), 256, 0, stream>>>(
        h_a, w_out, b_out, nullptr, qlin, HH, DD);
    // 8. q/k/v projections from r
    gemm_k<0, false><<<dim3(R / 64, DD / 64), 256, 0, stream>>>(
        qlin, wq, bq, nullptr, qb, DD, DD);
    gemm_k<0, false><<<dim3(R / 64, DD / 64), 256, 0, stream>>>(
        qlin, wk, bk, nullptr, kb, DD, DD);
    gemm_k<0, false><<<dim3(R / 64, DD / 64), 256, 0, stream>>>(
        qlin, wv, bv, nullptr, vb, DD, DD);
    // 9. attention -> ob(->xm)
    swa_attn_k<<<dim3(TT, NHH, BB), 64, 0, stream>>>(qb, kb, vb, xm);
    // 10. out = (ob @ wo + bo)[t >= M]
    gemm_k<0, true><<<dim3(R / 64, DD / 64), 256, 0, stream>>>(
        xm, wo, bo, nullptr, out, DD, DD);
}

// Round 2
// 620.847 us; speedup vs baseline: 1.5855x; 1.5855x over previous
//
#include <hip/hip_runtime.h>
#include <math.h>
#include <stdint.h>

#define BB 2
#define SS 2048
#define DD 512
#define HH 1024
#define MMETA 64
#define KCONV 4
#define NHH 8
#define DHH 64
#define WINN 256
#define TT (MMETA + SS)     // 2112
#define BT (BB * TT)        // 4224

typedef __attribute__((ext_vector_type(8))) short short8v;   // 8 bf16 = 4 VGPR
typedef __attribute__((ext_vector_type(4))) float f32x4;

__device__ __forceinline__ unsigned short f2bf(float f) {
    union { float f; unsigned u; } c; c.f = f;
    unsigned u = c.u;
    unsigned r = (u + 0x7fffu + ((u >> 16) & 1u)) >> 16;   // RNE
    return (unsigned short)r;
}
__device__ __forceinline__ float bf2f(unsigned short h) {
    union { unsigned u; float f; } c; c.u = ((unsigned)h) << 16;
    return c.f;
}

__device__ __forceinline__ void gload_lds16(const void* g, void* l) {
    __builtin_amdgcn_global_load_lds(
        (const __attribute__((address_space(1))) unsigned int*)g,
        (__attribute__((address_space(3))) unsigned int*)l, 16, 0, 0);
}

// ---------------------------------------------------------------------------
// weight transpose + split:  W [K][N] fp32  ->  Wh/Wl [N][K] bf16
// ---------------------------------------------------------------------------
__global__ __launch_bounds__(256) void wsplit_k(
    const float* __restrict__ W, unsigned short* __restrict__ Wh,
    unsigned short* __restrict__ Wl, int K, int N)
{
    __shared__ float tile[64][65];
    const int tid = threadIdx.x;
    const int k0 = blockIdx.x * 64, n0 = blockIdx.y * 64;
    #pragma unroll
    for (int i = 0; i < 16; ++i) {
        int lin = i * 256 + tid;
        int kr = lin >> 6, nc = lin & 63;
        tile[kr][nc] = W[(size_t)(k0 + kr) * N + n0 + nc];
    }
    __syncthreads();
    #pragma unroll
    for (int i = 0; i < 16; ++i) {
        int lin = i * 256 + tid;
        int nr = lin >> 6, kc = lin & 63;
        float v = tile[kc][nr];
        unsigned short hi = f2bf(v);
        size_t idx = (size_t)(n0 + nr) * K + k0 + kc;
        Wh[idx] = hi;
        Wl[idx] = f2bf(v - bf2f(hi));
    }
}

// ---------------------------------------------------------------------------
// build xm = concat(meta, x) -> hi/lo bf16 [BT][D]
// ---------------------------------------------------------------------------
__global__ __launch_bounds__(256) void build_xm_k(
    const float* __restrict__ x, const float* __restrict__ meta,
    unsigned short* __restrict__ xh, unsigned short* __restrict__ xl)
{
    int idx = blockIdx.x * 256 + threadIdx.x;   // float4 index over BT*128
    if (idx >= BT * 128) return;
    int row = idx >> 7, c4 = idx & 127;
    int b = row >= TT;
    int t = row - b * TT;
    float4 v = (t < MMETA) ? ((const float4*)(meta + (size_t)t * DD))[c4]
                           : ((const float4*)(x + ((size_t)b * SS + (t - MMETA)) * DD))[c4];
    ushort4 h, lo;
    h.x = f2bf(v.x); lo.x = f2bf(v.x - bf2f(h.x));
    h.y = f2bf(v.y); lo.y = f2bf(v.y - bf2f(h.y));
    h.z = f2bf(v.z); lo.z = f2bf(v.z - bf2f(h.z));
    h.w = f2bf(v.w); lo.w = f2bf(v.w - bf2f(h.w));
    ((ushort4*)xh)[idx] = h;
    ((ushort4*)xl)[idx] = lo;
}

// ---------------------------------------------------------------------------
// bf16x3 MFMA GEMM:  C = epi( A @ W^T + bias [, res] )
//   A as hi/lo bf16 [M][K]; W as hi/lo bf16 [N][K] (pre-transposed)
//   BMx128 tile, BK=32, 256 thr (2x2 waves), wave tile (BM/2)x64
//   EPI: 0 bias->fp32 out; 1 silu->hi/lo out; 2 res+silu->hi/lo out
// ---------------------------------------------------------------------------
template<int BM, int EPI, bool DROPMETA>
__global__ __launch_bounds__(256, 2) void gemm_mfma_k(
    const unsigned short* __restrict__ Ah, const unsigned short* __restrict__ Al,
    const unsigned short* __restrict__ Wh, const unsigned short* __restrict__ Wl,
    const float* __restrict__ bias,
    const unsigned short* __restrict__ resh, const unsigned short* __restrict__ resl,
    float* __restrict__ outf, unsigned short* __restrict__ outh,
    unsigned short* __restrict__ outl, int K, int N)
{
    static_assert(BM == 64 || BM == 128, "");
    constexpr int MF = BM / 32;
    constexpr int ABYTES = BM * 64;      // A tile bytes (BM x 32 bf16)
    constexpr int BBYTES = 128 * 64;     // B tile bytes
    constexpr int BUFB = 2 * ABYTES + 2 * BBYTES;
    __shared__ short8v smem_v[(2 * BUFB) / 16];
    char* smem = (char*)smem_v;

    const int tid = threadIdx.x;
    const int l = tid & 63, wid = tid >> 6;
    const int wm = wid >> 1, wn = wid & 1;
    const int lr = l & 15, lg = l >> 4;
    const int row0 = blockIdx.x * BM;
    const int n0 = blockIdx.y * 128;

    const char* Ahg0 = (const char*)Ah + (size_t)row0 * K * 2;
    const char* Alg0 = (const char*)Al + (size_t)row0 * K * 2;
    const char* Whg  = (const char*)Wh + (size_t)n0 * K * 2;
    const char* Wlg  = (const char*)Wl + (size_t)n0 * K * 2;

    int a_off[MF], b_off[4];
    #pragma unroll
    for (int mf = 0; mf < MF; ++mf) {
        int r = wm * (BM / 2) + mf * 16 + lr;
        a_off[mf] = r * 64 + ((lg * 16) ^ ((r & 3) << 4));
    }
    #pragma unroll
    for (int nf = 0; nf < 4; ++nf) {
        int r = wn * 64 + nf * 16 + lr;
        b_off[nf] = r * 64 + ((lg * 16) ^ ((r & 3) << 4));
    }

    f32x4 acc[MF][4];
    #pragma unroll
    for (int mf = 0; mf < MF; ++mf)
        #pragma unroll
        for (int nf = 0; nf < 4; ++nf) acc[mf][nf] = (f32x4){0.f, 0.f, 0.f, 0.f};

    const int NT = K / 32;

    auto stage = [&](int buf, int t) {
        char* lb = smem + buf * BUFB;
        const size_t kb = (size_t)t * 64;    // byte offset of k0 within a row
        #pragma unroll
        for (int it = 0; it < ABYTES / 4096; ++it) {
            int off = (it * 256 + tid) * 16;
            int row = off >> 6;
            int sc = (off & 63) ^ ((row & 3) << 4);
            size_t gb = (size_t)row * (K * 2) + kb + sc;
            gload_lds16(Ahg0 + gb, lb + off);
            gload_lds16(Alg0 + gb, lb + ABYTES + off);
        }
        #pragma unroll
        for (int it = 0; it < BBYTES / 4096; ++it) {
            int off = (it * 256 + tid) * 16;
            int row = off >> 6;
            int sc = (off & 63) ^ ((row & 3) << 4);
            size_t gb = (size_t)row * (K * 2) + kb + sc;
            gload_lds16(Whg + gb, lb + 2 * ABYTES + off);
            gload_lds16(Wlg + gb, lb + 2 * ABYTES + BBYTES + off);
        }
    };

    stage(0, 0);
    __syncthreads();

    int cur = 0;
    for (int t = 0; t < NT; ++t) {
        if (t + 1 < NT) stage(cur ^ 1, t + 1);
        char* lb = smem + cur * BUFB;
        short8v ah[MF], al[MF], bh[4], bl[4];
        #pragma unroll
        for (int mf = 0; mf < MF; ++mf) {
            ah[mf] = *(const short8v*)(lb + a_off[mf]);
            al[mf] = *(const short8v*)(lb + ABYTES + a_off[mf]);
        }
        #pragma unroll
        for (int nf = 0; nf < 4; ++nf) {
            bh[nf] = *(const short8v*)(lb + 2 * ABYTES + b_off[nf]);
            bl[nf] = *(const short8v*)(lb + 2 * ABYTES + BBYTES + b_off[nf]);
        }
        #pragma unroll
        for (int mf = 0; mf < MF; ++mf)
            #pragma unroll
            for (int nf = 0; nf < 4; ++nf) {
                acc[mf][nf] = __builtin_amdgcn_mfma_f32_16x16x32_bf16(ah[mf], bh[nf], acc[mf][nf], 0, 0, 0);
                acc[mf][nf] = __builtin_amdgcn_mfma_f32_16x16x32_bf16(ah[mf], bl[nf], acc[mf][nf], 0, 0, 0);
                acc[mf][nf] = __builtin_amdgcn_mfma_f32_16x16x32_bf16(al[mf], bh[nf], acc[mf][nf], 0, 0, 0);
            }
        __syncthreads();
        cur ^= 1;
    }

    // epilogue: C/D layout col = lane&15, row = (lane>>4)*4 + reg
    #pragma unroll
    for (int mf = 0; mf < MF; ++mf) {
        #pragma unroll
        for (int nf = 0; nf < 4; ++nf) {
            int col = n0 + wn * 64 + nf * 16 + lr;
            float bv = bias[col];
            #pragma unroll
            for (int j = 0; j < 4; ++j) {
                int row = row0 + wm * (BM / 2) + mf * 16 + lg * 4 + j;
                float v = acc[mf][nf][j] + bv;
                if (EPI >= 1) v = v / (1.f + __expf(-v));
                size_t idx = (size_t)row * N + col;
                if (EPI == 2) v += bf2f(resh[idx]) + bf2f(resl[idx]);
                if (EPI == 0) {
                    if (DROPMETA) {
                        int b = row >= TT;
                        int t2 = row - b * TT;
                        if (t2 >= MMETA)
                            outf[((size_t)b * SS + (t2 - MMETA)) * N + col] = v;
                    } else {
                        outf[idx] = v;
                    }
                } else {
                    unsigned short hi = f2bf(v);
                    outh[idx] = hi;
                    outl[idx] = f2bf(v - bf2f(hi));
                }
            }
        }
    }
}

// ---------------------------------------------------------------------------
// causal depthwise conv (K=4) + L2 normalize; out as hi/lo bf16
// ---------------------------------------------------------------------------
__global__ __launch_bounds__(256) void conv_norm_k(
    const float* __restrict__ qlin, const float* __restrict__ convw,
    unsigned short* __restrict__ qh, unsigned short* __restrict__ ql)
{
    const int row = blockIdx.x;
    const int b = row >= TT;
    const int t = row - b * TT;
    const int tid = threadIdx.x;

    float vals[2];
    float ss = 0.f;
    #pragma unroll
    for (int e = 0; e < 2; ++e) {
        int d = tid + e * 256;
        float acc = 0.f;
        #pragma unroll
        for (int k = 0; k < KCONV; ++k) {
            int tt = t - (KCONV - 1) + k;
            if (tt >= 0)
                acc += qlin[((size_t)b * TT + tt) * DD + d] * convw[k * DD + d];
        }
        vals[e] = acc;
        ss += acc * acc;
    }
    #pragma unroll
    for (int off = 32; off > 0; off >>= 1)
        ss += __shfl_xor(ss, off);
    __shared__ float red[4];
    if ((tid & 63) == 0) red[tid >> 6] = ss;
    __syncthreads();
    float total = red[0] + red[1] + red[2] + red[3];
    float inv = 1.f / fmaxf(sqrtf(total), 1e-12f);
    #pragma unroll
    for (int e = 0; e < 2; ++e) {
        int d = tid + e * 256;
        float v = vals[e] * inv;
        unsigned short hi = f2bf(v);
        qh[(size_t)row * DD + d] = hi;
        ql[(size_t)row * DD + d] = f2bf(v - bf2f(hi));
    }
}

// ---------------------------------------------------------------------------
// sliding-window attention; 4 queries per 256-thr block; out hi/lo bf16
// ---------------------------------------------------------------------------
__global__ __launch_bounds__(256) void swa_attn_k(
    const float* __restrict__ qb, const float* __restrict__ kb,
    const float* __restrict__ vb, unsigned short* __restrict__ oh,
    unsigned short* __restrict__ ol)
{
    const int w = threadIdx.x >> 6, lane = threadIdx.x & 63;
    const int i = blockIdx.x * 4 + w;
    const int h = blockIdx.y, b = blockIdx.z;

    __shared__ float qs[4][64];
    __shared__ float ps[4][256];

    const size_t hoff = (size_t)h * DHH;
    qs[w][lane] = qb[((size_t)b * TT + i) * DD + hoff + lane];
    __syncthreads();

    const int jstart = (i - WINN + 1 > 0) ? (i - WINN + 1) : 0;
    const int cnt = i - jstart + 1;

    float s[4];
    float m = -1e30f;
    const float4* qs4 = (const float4*)qs[w];
    #pragma unroll
    for (int kk = 0; kk < 4; ++kk) {
        int rel = kk * 64 + lane;
        if (rel < cnt) {
            const float4* kr4 = (const float4*)(kb + ((size_t)b * TT + jstart + rel) * DD + hoff);
            float acc = 0.f;
            #pragma unroll
            for (int d4 = 0; d4 < DHH / 4; ++d4) {
                float4 kv = kr4[d4], qv = qs4[d4];
                acc += qv.x * kv.x + qv.y * kv.y + qv.z * kv.z + qv.w * kv.w;
            }
            s[kk] = acc * 0.125f;
        } else {
            s[kk] = -1e30f;
        }
        m = fmaxf(m, s[kk]);
    }
    #pragma unroll
    for (int off = 32; off > 0; off >>= 1)
        m = fmaxf(m, __shfl_xor(m, off));

    float lsum = 0.f;
    #pragma unroll
    for (int kk = 0; kk < 4; ++kk) {
        int rel = kk * 64 + lane;
        float p = (rel < cnt) ? __expf(s[kk] - m) : 0.f;
        ps[w][rel] = p;
        lsum += p;
    }
    #pragma unroll
    for (int off = 32; off > 0; off >>= 1)
        lsum += __shfl_xor(lsum, off);
    __syncthreads();

    float acc = 0.f;
    for (int j = 0; j < cnt; ++j)
        acc += ps[w][j] * vb[((size_t)b * TT + jstart + j) * DD + hoff + lane];

    float o = acc / lsum;
    size_t idx = ((size_t)b * TT + i) * DD + hoff + lane;
    unsigned short hi = f2bf(o);
    oh[idx] = hi;
    ol[idx] = f2bf(o - bf2f(hi));
}

// ---------------------------------------------------------------------------
// Launch
// ---------------------------------------------------------------------------
extern "C" void kernel_launch(void* const* d_in, const int* in_sizes, int n_in,
                              void* d_out, int out_size, void* d_ws, size_t ws_size,
                              hipStream_t stream)
{
    const float* x       = (const float*)d_in[0];
    const float* meta    = (const float*)d_in[1];
    const float* qp_w    = (const float*)d_in[2];
    const float* qp_b    = (const float*)d_in[3];
    const float* qp_conv = (const float*)d_in[4];
    const float* w_in    = (const float*)d_in[5];
    const float* b_in    = (const float*)d_in[6];
    const float* w_hid   = (const float*)d_in[7];
    const float* b_hid   = (const float*)d_in[8];
    const float* w_out   = (const float*)d_in[9];
    const float* b_out   = (const float*)d_in[10];
    const float* wq      = (const float*)d_in[11];
    const float* bq      = (const float*)d_in[12];
    const float* wk      = (const float*)d_in[13];
    const float* bk      = (const float*)d_in[14];
    const float* wv      = (const float*)d_in[15];
    const float* bv      = (const float*)d_in[16];
    const float* wo      = (const float*)d_in[17];
    const float* bo      = (const float*)d_in[18];
    float* out = (float*)d_out;

    typedef unsigned short us;
    char* p = (char*)d_ws;
    auto alloc = [&](size_t n) { char* r = p; p += (n + 255) & ~(size_t)255; return r; };

    // split weights (hi/lo, transposed [N][K])
    us* wqp_h  = (us*)alloc(512 * 512 * 2);  us* wqp_l  = (us*)alloc(512 * 512 * 2);
    us* win_h  = (us*)alloc(512 * 1024 * 2); us* win_l  = (us*)alloc(512 * 1024 * 2);
    us* whid0_h = (us*)alloc(1024 * 1024 * 2); us* whid0_l = (us*)alloc(1024 * 1024 * 2);
    us* whid1_h = (us*)alloc(1024 * 1024 * 2); us* whid1_l = (us*)alloc(1024 * 1024 * 2);
    us* wout_h = (us*)alloc(1024 * 512 * 2); us* wout_l = (us*)alloc(1024 * 512 * 2);
    us* wq_h   = (us*)alloc(512 * 512 * 2);  us* wq_l   = (us*)alloc(512 * 512 * 2);
    us* wk_h   = (us*)alloc(512 * 512 * 2);  us* wk_l   = (us*)alloc(512 * 512 * 2);
    us* wv_h   = (us*)alloc(512 * 512 * 2);  us* wv_l   = (us*)alloc(512 * 512 * 2);
    us* wo_h   = (us*)alloc(512 * 512 * 2);  us* wo_l   = (us*)alloc(512 * 512 * 2);

    const size_t HALF = (size_t)BT * 512 * 2;   // 4325376 bytes
    char* RA = alloc(2 * HALF);   // xm hi/lo ; later qb (fp32)
    char* RB = alloc(2 * HALF);   // qlin (fp32) ; later kb (fp32)
    char* RC = alloc(2 * HALF);   // qn hi/lo ; later r hi/lo
    char* RD = alloc(4 * HALF);   // ha hi/lo ; later hc hi/lo ; later ob hi/lo
    char* RE = alloc(4 * HALF);   // hb hi/lo
    char* RF = alloc(2 * HALF);   // vb (fp32)

    us* xm_h = (us*)RA;          us* xm_l = (us*)(RA + HALF);
    float* qlin = (float*)RB;
    us* qn_h = (us*)RC;          us* qn_l = (us*)(RC + HALF);
    us* ha_h = (us*)RD;          us* ha_l = (us*)(RD + 2 * HALF);
    us* hb_h = (us*)RE;          us* hb_l = (us*)(RE + 2 * HALF);
    us* hc_h = ha_h;             us* hc_l = ha_l;
    us* r_h  = qn_h;             us* r_l  = qn_l;
    float* qb = (float*)RA;
    float* kb = (float*)RB;
    float* vb = (float*)RF;
    us* ob_h = (us*)RD;          us* ob_l = (us*)(RD + HALF);

    // --- weight splits ---
    wsplit_k<<<dim3(8, 8),  256, 0, stream>>>(qp_w,  wqp_h,  wqp_l,  512, 512);
    wsplit_k<<<dim3(8, 16), 256, 0, stream>>>(w_in,  win_h,  win_l,  512, 1024);
    wsplit_k<<<dim3(16, 16), 256, 0, stream>>>(w_hid, whid0_h, whid0_l, 1024, 1024);
    wsplit_k<<<dim3(16, 16), 256, 0, stream>>>(w_hid + (size_t)1024 * 1024, whid1_h, whid1_l, 1024, 1024);
    wsplit_k<<<dim3(16, 8), 256, 0, stream>>>(w_out, wout_h, wout_l, 1024, 512);
    wsplit_k<<<dim3(8, 8),  256, 0, stream>>>(wq, wq_h, wq_l, 512, 512);
    wsplit_k<<<dim3(8, 8),  256, 0, stream>>>(wk, wk_h, wk_l, 512, 512);
    wsplit_k<<<dim3(8, 8),  256, 0, stream>>>(wv, wv_h, wv_l, 512, 512);
    wsplit_k<<<dim3(8, 8),  256, 0, stream>>>(wo, wo_h, wo_l, 512, 512);

    // --- pipeline ---
    build_xm_k<<<(BT * 128 + 255) / 256, 256, 0, stream>>>(x, meta, xm_h, xm_l);

    // qlin = xm @ qp_w + b  (fp32 out)
    gemm_mfma_k<64, 0, false><<<dim3(66, 4), 256, 0, stream>>>(
        xm_h, xm_l, wqp_h, wqp_l, qp_b, nullptr, nullptr, qlin, nullptr, nullptr, 512, 512);
    // qn = l2norm(conv(qlin))
    conv_norm_k<<<BT, 256, 0, stream>>>(qlin, qp_conv, qn_h, qn_l);
    // ha = silu(qn @ w_in + b_in)
    gemm_mfma_k<128, 1, false><<<dim3(33, 8), 256, 0, stream>>>(
        qn_h, qn_l, win_h, win_l, b_in, nullptr, nullptr, nullptr, ha_h, ha_l, 512, 1024);
    // hb = ha + silu(ha @ w_hid0 + b_hid0)
    gemm_mfma_k<128, 2, false><<<dim3(33, 8), 256, 0, stream>>>(
        ha_h, ha_l, whid0_h, whid0_l, b_hid, ha_h, ha_l, nullptr, hb_h, hb_l, 1024, 1024);
    // hc = hb + silu(hb @ w_hid1 + b_hid1)
    gemm_mfma_k<128, 2, false><<<dim3(33, 8), 256, 0, stream>>>(
        hb_h, hb_l, whid1_h, whid1_l, b_hid + HH, hb_h, hb_l, nullptr, hc_h, hc_l, 1024, 1024);
    // r = silu(hc @ w_out + b_out)
    gemm_mfma_k<64, 1, false><<<dim3(66, 4), 256, 0, stream>>>(
        hc_h, hc_l, wout_h, wout_l, b_out, nullptr, nullptr, nullptr, r_h, r_l, 1024, 512);
    // q/k/v projections (fp32 out)
    gemm_mfma_k<64, 0, false><<<dim3(66, 4), 256, 0, stream>>>(
        r_h, r_l, wq_h, wq_l, bq, nullptr, nullptr, qb, nullptr, nullptr, 512, 512);
    gemm_mfma_k<64, 0, false><<<dim3(66, 4), 256, 0, stream>>>(
        r_h, r_l, wk_h, wk_l, bk, nullptr, nullptr, kb, nullptr, nullptr, 512, 512);
    gemm_mfma_k<64, 0, false><<<dim3(66, 4), 256, 0, stream>>>(
        r_h, r_l, wv_h, wv_l, bv, nullptr, nullptr, vb, nullptr, nullptr, 512, 512);
    // attention
    swa_attn_k<<<dim3(TT / 4, NHH, BB), 256, 0, stream>>>(qb, kb, vb, ob_h, ob_l);
    // out = (ob @ wo + bo)[t >= M]
    gemm_mfma_k<64, 0, true><<<dim3(66, 4), 256, 0, stream>>>(
        ob_h, ob_l, wo_h, wo_l, bo, nullptr, nullptr, out, nullptr, nullptr, 512, 512);
}

// Round 3
// 324.389 us; speedup vs baseline: 3.0344x; 1.9139x over previous
//
#include <hip/hip_runtime.h>
#include <math.h>
#include <stdint.h>

#define BB 2
#define SS 2048
#define DD 512
#define HH 1024
#define MMETA 64
#define KCONV 4
#define NHH 8
#define DHH 64
#define WINN 256
#define TT (MMETA + SS)     // 2112
#define BT (BB * TT)        // 4224
#define QKV_N 1536

typedef __attribute__((ext_vector_type(8))) short short8v;   // 8 bf16 = 4 VGPR
typedef __attribute__((ext_vector_type(4))) float f32x4;

__device__ __forceinline__ unsigned short f2bf(float f) {
    union { float f; unsigned u; } c; c.f = f;
    unsigned u = c.u;
    unsigned r = (u + 0x7fffu + ((u >> 16) & 1u)) >> 16;   // RNE
    return (unsigned short)r;
}
__device__ __forceinline__ float bf2f(unsigned short h) {
    union { unsigned u; float f; } c; c.u = ((unsigned)h) << 16;
    return c.f;
}

__device__ __forceinline__ void gload_lds16(const void* g, void* l) {
    __builtin_amdgcn_global_load_lds(
        (const __attribute__((address_space(1))) unsigned int*)g,
        (__attribute__((address_space(3))) unsigned int*)l, 16, 0, 0);
}

// ---------------------------------------------------------------------------
// weight transpose + split:  W [K][N] fp32  ->  Wh/Wl [N][K] bf16
// ---------------------------------------------------------------------------
__global__ __launch_bounds__(256) void wsplit_k(
    const float* __restrict__ W, unsigned short* __restrict__ Wh,
    unsigned short* __restrict__ Wl, int K, int N)
{
    __shared__ float tile[64][65];
    const int tid = threadIdx.x;
    const int k0 = blockIdx.x * 64, n0 = blockIdx.y * 64;
    #pragma unroll
    for (int i = 0; i < 16; ++i) {
        int lin = i * 256 + tid;
        int kr = lin >> 6, nc = lin & 63;
        tile[kr][nc] = W[(size_t)(k0 + kr) * N + n0 + nc];
    }
    __syncthreads();
    #pragma unroll
    for (int i = 0; i < 16; ++i) {
        int lin = i * 256 + tid;
        int nr = lin >> 6, kc = lin & 63;
        float v = tile[kc][nr];
        unsigned short hi = f2bf(v);
        size_t idx = (size_t)(n0 + nr) * K + k0 + kc;
        Wh[idx] = hi;
        Wl[idx] = f2bf(v - bf2f(hi));
    }
}

// ---------------------------------------------------------------------------
// concat q/k/v biases into one [1536] buffer
// ---------------------------------------------------------------------------
__global__ __launch_bounds__(256) void bias_concat_k(
    const float* __restrict__ bq, const float* __restrict__ bk,
    const float* __restrict__ bv, float* __restrict__ o)
{
    int i = blockIdx.x * 256 + threadIdx.x;
    if (i >= QKV_N) return;
    float v;
    if (i < 512) v = bq[i];
    else if (i < 1024) v = bk[i - 512];
    else v = bv[i - 1024];
    o[i] = v;
}

// ---------------------------------------------------------------------------
// build xm = concat(meta, x) -> hi/lo bf16 [BT][D]
// ---------------------------------------------------------------------------
__global__ __launch_bounds__(256) void build_xm_k(
    const float* __restrict__ x, const float* __restrict__ meta,
    unsigned short* __restrict__ xh, unsigned short* __restrict__ xl)
{
    int idx = blockIdx.x * 256 + threadIdx.x;   // float4 index over BT*128
    if (idx >= BT * 128) return;
    int row = idx >> 7, c4 = idx & 127;
    int b = row >= TT;
    int t = row - b * TT;
    float4 v = (t < MMETA) ? ((const float4*)(meta + (size_t)t * DD))[c4]
                           : ((const float4*)(x + ((size_t)b * SS + (t - MMETA)) * DD))[c4];
    ushort4 h, lo;
    h.x = f2bf(v.x); lo.x = f2bf(v.x - bf2f(h.x));
    h.y = f2bf(v.y); lo.y = f2bf(v.y - bf2f(h.y));
    h.z = f2bf(v.z); lo.z = f2bf(v.z - bf2f(h.z));
    h.w = f2bf(v.w); lo.w = f2bf(v.w - bf2f(h.w));
    ((ushort4*)xh)[idx] = h;
    ((ushort4*)xl)[idx] = lo;
}

// ---------------------------------------------------------------------------
// bf16x3 MFMA GEMM:  C = epi( A @ W^T + bias [, res] )
//   EPI: 0 bias->fp32 out; 1 silu->hi/lo; 2 res+silu->hi/lo; 3 bias->hi/lo
// ---------------------------------------------------------------------------
template<int BM, int EPI, bool DROPMETA>
__global__ __launch_bounds__(256, 2) void gemm_mfma_k(
    const unsigned short* __restrict__ Ah, const unsigned short* __restrict__ Al,
    const unsigned short* __restrict__ Wh, const unsigned short* __restrict__ Wl,
    const float* __restrict__ bias,
    const unsigned short* __restrict__ resh, const unsigned short* __restrict__ resl,
    float* __restrict__ outf, unsigned short* __restrict__ outh,
    unsigned short* __restrict__ outl, int K, int N)
{
    static_assert(BM == 64 || BM == 128, "");
    constexpr int MF = BM / 32;
    constexpr int ABYTES = BM * 64;      // A tile bytes (BM x 32 bf16)
    constexpr int BBYTES = 128 * 64;     // B tile bytes
    constexpr int BUFB = 2 * ABYTES + 2 * BBYTES;
    __shared__ short8v smem_v[(2 * BUFB) / 16];
    char* smem = (char*)smem_v;

    const int tid = threadIdx.x;
    const int l = tid & 63, wid = tid >> 6;
    const int wm = wid >> 1, wn = wid & 1;
    const int lr = l & 15, lg = l >> 4;
    const int row0 = blockIdx.x * BM;
    const int n0 = blockIdx.y * 128;

    const char* Ahg0 = (const char*)Ah + (size_t)row0 * K * 2;
    const char* Alg0 = (const char*)Al + (size_t)row0 * K * 2;
    const char* Whg  = (const char*)Wh + (size_t)n0 * K * 2;
    const char* Wlg  = (const char*)Wl + (size_t)n0 * K * 2;

    int a_off[MF], b_off[4];
    #pragma unroll
    for (int mf = 0; mf < MF; ++mf) {
        int r = wm * (BM / 2) + mf * 16 + lr;
        a_off[mf] = r * 64 + ((lg * 16) ^ ((r & 3) << 4));
    }
    #pragma unroll
    for (int nf = 0; nf < 4; ++nf) {
        int r = wn * 64 + nf * 16 + lr;
        b_off[nf] = r * 64 + ((lg * 16) ^ ((r & 3) << 4));
    }

    f32x4 acc[MF][4];
    #pragma unroll
    for (int mf = 0; mf < MF; ++mf)
        #pragma unroll
        for (int nf = 0; nf < 4; ++nf) acc[mf][nf] = (f32x4){0.f, 0.f, 0.f, 0.f};

    const int NT = K / 32;

    auto stage = [&](int buf, int t) {
        char* lb = smem + buf * BUFB;
        const size_t kb = (size_t)t * 64;
        #pragma unroll
        for (int it = 0; it < ABYTES / 4096; ++it) {
            int off = (it * 256 + tid) * 16;
            int row = off >> 6;
            int sc = (off & 63) ^ ((row & 3) << 4);
            size_t gb = (size_t)row * (K * 2) + kb + sc;
            gload_lds16(Ahg0 + gb, lb + off);
            gload_lds16(Alg0 + gb, lb + ABYTES + off);
        }
        #pragma unroll
        for (int it = 0; it < BBYTES / 4096; ++it) {
            int off = (it * 256 + tid) * 16;
            int row = off >> 6;
            int sc = (off & 63) ^ ((row & 3) << 4);
            size_t gb = (size_t)row * (K * 2) + kb + sc;
            gload_lds16(Whg + gb, lb + 2 * ABYTES + off);
            gload_lds16(Wlg + gb, lb + 2 * ABYTES + BBYTES + off);
        }
    };

    stage(0, 0);
    __syncthreads();

    int cur = 0;
    for (int t = 0; t < NT; ++t) {
        if (t + 1 < NT) stage(cur ^ 1, t + 1);
        char* lb = smem + cur * BUFB;
        short8v ah[MF], al[MF], bh[4], bl[4];
        #pragma unroll
        for (int mf = 0; mf < MF; ++mf) {
            ah[mf] = *(const short8v*)(lb + a_off[mf]);
            al[mf] = *(const short8v*)(lb + ABYTES + a_off[mf]);
        }
        #pragma unroll
        for (int nf = 0; nf < 4; ++nf) {
            bh[nf] = *(const short8v*)(lb + 2 * ABYTES + b_off[nf]);
            bl[nf] = *(const short8v*)(lb + 2 * ABYTES + BBYTES + b_off[nf]);
        }
        #pragma unroll
        for (int mf = 0; mf < MF; ++mf)
            #pragma unroll
            for (int nf = 0; nf < 4; ++nf) {
                acc[mf][nf] = __builtin_amdgcn_mfma_f32_16x16x32_bf16(ah[mf], bh[nf], acc[mf][nf], 0, 0, 0);
                acc[mf][nf] = __builtin_amdgcn_mfma_f32_16x16x32_bf16(ah[mf], bl[nf], acc[mf][nf], 0, 0, 0);
                acc[mf][nf] = __builtin_amdgcn_mfma_f32_16x16x32_bf16(al[mf], bh[nf], acc[mf][nf], 0, 0, 0);
            }
        __syncthreads();
        cur ^= 1;
    }

    #pragma unroll
    for (int mf = 0; mf < MF; ++mf) {
        #pragma unroll
        for (int nf = 0; nf < 4; ++nf) {
            int col = n0 + wn * 64 + nf * 16 + lr;
            float bv = bias[col];
            #pragma unroll
            for (int j = 0; j < 4; ++j) {
                int row = row0 + wm * (BM / 2) + mf * 16 + lg * 4 + j;
                float v = acc[mf][nf][j] + bv;
                if (EPI == 1 || EPI == 2) v = v / (1.f + __expf(-v));
                size_t idx = (size_t)row * N + col;
                if (EPI == 2) v += bf2f(resh[idx]) + bf2f(resl[idx]);
                if (EPI == 0) {
                    if (DROPMETA) {
                        int b = row >= TT;
                        int t2 = row - b * TT;
                        if (t2 >= MMETA)
                            outf[((size_t)b * SS + (t2 - MMETA)) * N + col] = v;
                    } else {
                        outf[idx] = v;
                    }
                } else {
                    unsigned short hi = f2bf(v);
                    outh[idx] = hi;
                    outl[idx] = f2bf(v - bf2f(hi));
                }
            }
        }
    }
}

// ---------------------------------------------------------------------------
// causal depthwise conv (K=4) + L2 normalize; out as hi/lo bf16
// ---------------------------------------------------------------------------
__global__ __launch_bounds__(256) void conv_norm_k(
    const float* __restrict__ qlin, const float* __restrict__ convw,
    unsigned short* __restrict__ qh, unsigned short* __restrict__ ql)
{
    const int row = blockIdx.x;
    const int b = row >= TT;
    const int t = row - b * TT;
    const int tid = threadIdx.x;

    float vals[2];
    float ss = 0.f;
    #pragma unroll
    for (int e = 0; e < 2; ++e) {
        int d = tid + e * 256;
        float acc = 0.f;
        #pragma unroll
        for (int k = 0; k < KCONV; ++k) {
            int tt = t - (KCONV - 1) + k;
            if (tt >= 0)
                acc += qlin[((size_t)b * TT + tt) * DD + d] * convw[k * DD + d];
        }
        vals[e] = acc;
        ss += acc * acc;
    }
    #pragma unroll
    for (int off = 32; off > 0; off >>= 1)
        ss += __shfl_xor(ss, off);
    __shared__ float red[4];
    if ((tid & 63) == 0) red[tid >> 6] = ss;
    __syncthreads();
    float total = red[0] + red[1] + red[2] + red[3];
    float inv = 1.f / fmaxf(sqrtf(total), 1e-12f);
    #pragma unroll
    for (int e = 0; e < 2; ++e) {
        int d = tid + e * 256;
        float v = vals[e] * inv;
        unsigned short hi = f2bf(v);
        qh[(size_t)row * DD + d] = hi;
        ql[(size_t)row * DD + d] = f2bf(v - bf2f(hi));
    }
}

// ---------------------------------------------------------------------------
// Flash sliding-window attention, MFMA.
//   Block: 64 queries x 1 head x 1 batch, 4 waves (wave = 16 query rows).
//   qkv: [BT][1536] hi/lo bf16 (q cols 0-511, k 512-1023, v 1024-1535).
//   Iterates 5 key tiles of 64 covering [q0-256, q0+63], online softmax.
// ---------------------------------------------------------------------------
__global__ __launch_bounds__(256, 2) void swa_flash_k(
    const unsigned short* __restrict__ qkvh, const unsigned short* __restrict__ qkvl,
    unsigned short* __restrict__ oh, unsigned short* __restrict__ ol)
{
    // LDS: Kh[64][64]swz 8192 | Kl 8192 | Vth[64][72] 9216 | Vtl 9216 | P 4x2304
    __shared__ short8v lds_v[44032 / 16];
    char* lds = (char*)lds_v;
    char* Kh_lds = lds;
    char* Kl_lds = lds + 8192;
    char* Vh_lds = lds + 16384;
    char* Vl_lds = lds + 16384 + 9216;
    char* P_lds  = lds + 16384 + 18432;

    const int tid = threadIdx.x;
    const int lane = tid & 63, w = tid >> 6;
    const int l15 = lane & 15, lg = lane >> 4;
    const int q0 = blockIdx.x * 64;
    const int h = blockIdx.y, b = blockIdx.z;
    const int rowbase = b * TT;

    // Q fragments in registers (A-frag: row = lane&15, k = lg*8..+7)
    const int qrow = rowbase + q0 + w * 16 + l15;
    short8v qhf[2], qlf[2];
    #pragma unroll
    for (int kh = 0; kh < 2; ++kh) {
        size_t off = (size_t)qrow * QKV_N + h * 64 + kh * 32 + lg * 8;
        qhf[kh] = *(const short8v*)(qkvh + off);
        qlf[kh] = *(const short8v*)(qkvl + off);
    }

    f32x4 o_acc[4];
    #pragma unroll
    for (int td = 0; td < 4; ++td) o_acc[td] = (f32x4){0.f, 0.f, 0.f, 0.f};
    float m_r[4], l_r[4];
    #pragma unroll
    for (int r = 0; r < 4; ++r) { m_r[r] = -1e30f; l_r[r] = 0.f; }

    char* Pw = P_lds + w * 2304;   // per-wave [16][72] bf16

    for (int kt = 0; kt < 5; ++kt) {
        const int kst = q0 - 256 + kt * 64;
        if (kst + 64 <= 0) continue;
        __syncthreads();
        // --- stage K (hi/lo) via global_load_lds, XOR-swizzled source ---
        #pragma unroll
        for (int it = 0; it < 2; ++it) {
            int lin = it * 256 + tid;
            int r = lin >> 3, seg = lin & 7;
            int gr = kst + r; gr = gr < 0 ? 0 : gr;
            int colb = (seg * 16) ^ ((r & 7) << 4);
            size_t gb = ((size_t)(rowbase + gr) * QKV_N + 512 + h * 64) * 2 + colb;
            gload_lds16((const char*)qkvh + gb, Kh_lds + lin * 16);
            gload_lds16((const char*)qkvl + gb, Kl_lds + lin * 16);
        }
        // --- stage V transposed (reg -> LDS [d][j], pad 72) ---
        #pragma unroll
        for (int c = 0; c < 2; ++c) {
            int lin = c * 256 + tid;
            int r = lin >> 3, seg = lin & 7;
            int gr = kst + r; gr = gr < 0 ? 0 : gr;
            size_t goff = (size_t)(rowbase + gr) * QKV_N + 1024 + h * 64 + seg * 8;
            short8v vh = *(const short8v*)(qkvh + goff);
            short8v vl = *(const short8v*)(qkvl + goff);
            #pragma unroll
            for (int e = 0; e < 8; ++e) {
                ((unsigned short*)Vh_lds)[(seg * 8 + e) * 72 + r] = (unsigned short)vh[e];
                ((unsigned short*)Vl_lds)[(seg * 8 + e) * 72 + r] = (unsigned short)vl[e];
            }
        }
        __syncthreads();

        // --- S = Q K^T (bf16x3) ---
        f32x4 s_fr[4];
        #pragma unroll
        for (int tj = 0; tj < 4; ++tj) s_fr[tj] = (f32x4){0.f, 0.f, 0.f, 0.f};
        #pragma unroll
        for (int tj = 0; tj < 4; ++tj) {
            int j = tj * 16 + l15;
            #pragma unroll
            for (int kh = 0; kh < 2; ++kh) {
                int colb = (kh * 64 + lg * 16) ^ ((j & 7) << 4);
                short8v kbh = *(const short8v*)(Kh_lds + j * 128 + colb);
                short8v kbl = *(const short8v*)(Kl_lds + j * 128 + colb);
                s_fr[tj] = __builtin_amdgcn_mfma_f32_16x16x32_bf16(qhf[kh], kbh, s_fr[tj], 0, 0, 0);
                s_fr[tj] = __builtin_amdgcn_mfma_f32_16x16x32_bf16(qhf[kh], kbl, s_fr[tj], 0, 0, 0);
                s_fr[tj] = __builtin_amdgcn_mfma_f32_16x16x32_bf16(qlf[kh], kbh, s_fr[tj], 0, 0, 0);
            }
        }
        // --- mask + scale; rows i = q0 + w*16 + lg*4 + r, cols j = kst + tj*16 + l15
        #pragma unroll
        for (int tj = 0; tj < 4; ++tj) {
            int j = kst + tj * 16 + l15;
            #pragma unroll
            for (int r = 0; r < 4; ++r) {
                int i = q0 + w * 16 + lg * 4 + r;
                bool valid = (j >= 0) && (j <= i) && (i - j < WINN);
                s_fr[tj][r] = valid ? s_fr[tj][r] * 0.125f : -1e30f;
            }
        }
        // --- online softmax update ---
        float mx[4];
        #pragma unroll
        for (int r = 0; r < 4; ++r) {
            mx[r] = fmaxf(fmaxf(s_fr[0][r], s_fr[1][r]), fmaxf(s_fr[2][r], s_fr[3][r]));
            #pragma unroll
            for (int msk = 1; msk <= 8; msk <<= 1)
                mx[r] = fmaxf(mx[r], __shfl_xor(mx[r], msk));
            float mn = fmaxf(m_r[r], mx[r]);
            float sc = __expf(m_r[r] - mn);
            m_r[r] = mn;
            l_r[r] *= sc;
            #pragma unroll
            for (int td = 0; td < 4; ++td) o_acc[td][r] *= sc;
        }
        float rs[4] = {0.f, 0.f, 0.f, 0.f};
        #pragma unroll
        for (int tj = 0; tj < 4; ++tj) {
            #pragma unroll
            for (int r = 0; r < 4; ++r) {
                float p = __expf(s_fr[tj][r] - m_r[r]);
                rs[r] += p;
                ((unsigned short*)Pw)[(lg * 4 + r) * 72 + tj * 16 + l15] = f2bf(p);
            }
        }
        #pragma unroll
        for (int r = 0; r < 4; ++r) {
            #pragma unroll
            for (int msk = 1; msk <= 8; msk <<= 1)
                rs[r] += __shfl_xor(rs[r], msk);
            l_r[r] += rs[r];
        }
        // --- PV: O += P @ V  (P bf16, V hi/lo) ---
        short8v pa[2];
        #pragma unroll
        for (int jh = 0; jh < 2; ++jh)
            pa[jh] = *(const short8v*)(Pw + l15 * 144 + jh * 64 + lg * 16);
        #pragma unroll
        for (int td = 0; td < 4; ++td) {
            #pragma unroll
            for (int jh = 0; jh < 2; ++jh) {
                int drow = td * 16 + l15;
                short8v vfh = *(const short8v*)(Vh_lds + drow * 144 + jh * 64 + lg * 16);
                short8v vfl = *(const short8v*)(Vl_lds + drow * 144 + jh * 64 + lg * 16);
                o_acc[td] = __builtin_amdgcn_mfma_f32_16x16x32_bf16(pa[jh], vfh, o_acc[td], 0, 0, 0);
                o_acc[td] = __builtin_amdgcn_mfma_f32_16x16x32_bf16(pa[jh], vfl, o_acc[td], 0, 0, 0);
            }
        }
    }

    // --- epilogue: divide by l, write hi/lo bf16 [BT][512] ---
    #pragma unroll
    for (int r = 0; r < 4; ++r) {
        float inv = 1.f / l_r[r];
        int row = rowbase + q0 + w * 16 + lg * 4 + r;
        #pragma unroll
        for (int td = 0; td < 4; ++td) {
            float v = o_acc[td][r] * inv;
            size_t idx = (size_t)row * DD + h * 64 + td * 16 + l15;
            unsigned short hi = f2bf(v);
            oh[idx] = hi;
            ol[idx] = f2bf(v - bf2f(hi));
        }
    }
}

// ---------------------------------------------------------------------------
// Launch
// ---------------------------------------------------------------------------
extern "C" void kernel_launch(void* const* d_in, const int* in_sizes, int n_in,
                              void* d_out, int out_size, void* d_ws, size_t ws_size,
                              hipStream_t stream)
{
    const float* x       = (const float*)d_in[0];
    const float* meta    = (const float*)d_in[1];
    const float* qp_w    = (const float*)d_in[2];
    const float* qp_b    = (const float*)d_in[3];
    const float* qp_conv = (const float*)d_in[4];
    const float* w_in    = (const float*)d_in[5];
    const float* b_in    = (const float*)d_in[6];
    const float* w_hid   = (const float*)d_in[7];
    const float* b_hid   = (const float*)d_in[8];
    const float* w_out   = (const float*)d_in[9];
    const float* b_out   = (const float*)d_in[10];
    const float* wq      = (const float*)d_in[11];
    const float* bq      = (const float*)d_in[12];
    const float* wk      = (const float*)d_in[13];
    const float* bk      = (const float*)d_in[14];
    const float* wv      = (const float*)d_in[15];
    const float* bv      = (const float*)d_in[16];
    const float* wo      = (const float*)d_in[17];
    const float* bo      = (const float*)d_in[18];
    float* out = (float*)d_out;

    typedef unsigned short us;
    char* p = (char*)d_ws;
    auto alloc = [&](size_t n) { char* r = p; p += (n + 255) & ~(size_t)255; return r; };

    // split weights (hi/lo, transposed [N][K])
    us* wqp_h   = (us*)alloc(512 * 512 * 2);   us* wqp_l   = (us*)alloc(512 * 512 * 2);
    us* win_h   = (us*)alloc(512 * 1024 * 2);  us* win_l   = (us*)alloc(512 * 1024 * 2);
    us* whid0_h = (us*)alloc(1024 * 1024 * 2); us* whid0_l = (us*)alloc(1024 * 1024 * 2);
    us* whid1_h = (us*)alloc(1024 * 1024 * 2); us* whid1_l = (us*)alloc(1024 * 1024 * 2);
    us* wout_h  = (us*)alloc(1024 * 512 * 2);  us* wout_l  = (us*)alloc(1024 * 512 * 2);
    us* wqkv_h  = (us*)alloc((size_t)QKV_N * 512 * 2);
    us* wqkv_l  = (us*)alloc((size_t)QKV_N * 512 * 2);
    us* wo_h    = (us*)alloc(512 * 512 * 2);   us* wo_l    = (us*)alloc(512 * 512 * 2);
    float* bqkv = (float*)alloc(QKV_N * 4);

    const size_t HALF = (size_t)BT * 512 * 2;   // 4.3 MB
    char* RA = alloc(2 * HALF);   // xm hi/lo  -> later ob hi/lo
    char* RB = alloc(2 * HALF);   // qlin fp32
    char* RC = alloc(2 * HALF);   // qn hi/lo -> r hi/lo
    char* RD = alloc(6 * HALF);   // ha hi/lo -> hc hi/lo -> qkv hi/lo
    char* RE = alloc(4 * HALF);   // hb hi/lo

    us* xm_h = (us*)RA;   us* xm_l = (us*)(RA + HALF);
    float* qlin = (float*)RB;
    us* qn_h = (us*)RC;   us* qn_l = (us*)(RC + HALF);
    us* ha_h = (us*)RD;   us* ha_l = (us*)(RD + 2 * HALF);
    us* hb_h = (us*)RE;   us* hb_l = (us*)(RE + 2 * HALF);
    us* hc_h = ha_h;      us* hc_l = ha_l;
    us* r_h  = qn_h;      us* r_l  = qn_l;
    us* qkv_h = (us*)RD;  us* qkv_l = (us*)(RD + 3 * HALF);
    us* ob_h = (us*)RA;   us* ob_l = (us*)(RA + HALF);

    // --- weight prep ---
    wsplit_k<<<dim3(8, 8),   256, 0, stream>>>(qp_w,  wqp_h,  wqp_l,  512, 512);
    wsplit_k<<<dim3(8, 16),  256, 0, stream>>>(w_in,  win_h,  win_l,  512, 1024);
    wsplit_k<<<dim3(16, 16), 256, 0, stream>>>(w_hid, whid0_h, whid0_l, 1024, 1024);
    wsplit_k<<<dim3(16, 16), 256, 0, stream>>>(w_hid + (size_t)1024 * 1024, whid1_h, whid1_l, 1024, 1024);
    wsplit_k<<<dim3(16, 8),  256, 0, stream>>>(w_out, wout_h, wout_l, 1024, 512);
    wsplit_k<<<dim3(8, 8),   256, 0, stream>>>(wq, wqkv_h,                wqkv_l,                512, 512);
    wsplit_k<<<dim3(8, 8),   256, 0, stream>>>(wk, wqkv_h + 512 * 512,    wqkv_l + 512 * 512,    512, 512);
    wsplit_k<<<dim3(8, 8),   256, 0, stream>>>(wv, wqkv_h + 2 * 512 * 512, wqkv_l + 2 * 512 * 512, 512, 512);
    wsplit_k<<<dim3(8, 8),   256, 0, stream>>>(wo, wo_h, wo_l, 512, 512);
    bias_concat_k<<<6, 256, 0, stream>>>(bq, bk, bv, bqkv);

    // --- pipeline ---
    build_xm_k<<<(BT * 128 + 255) / 256, 256, 0, stream>>>(x, meta, xm_h, xm_l);

    gemm_mfma_k<64, 0, false><<<dim3(66, 4), 256, 0, stream>>>(
        xm_h, xm_l, wqp_h, wqp_l, qp_b, nullptr, nullptr, qlin, nullptr, nullptr, 512, 512);
    conv_norm_k<<<BT, 256, 0, stream>>>(qlin, qp_conv, qn_h, qn_l);
    gemm_mfma_k<128, 1, false><<<dim3(33, 8), 256, 0, stream>>>(
        qn_h, qn_l, win_h, win_l, b_in, nullptr, nullptr, nullptr, ha_h, ha_l, 512, 1024);
    gemm_mfma_k<128, 2, false><<<dim3(33, 8), 256, 0, stream>>>(
        ha_h, ha_l, whid0_h, whid0_l, b_hid, ha_h, ha_l, nullptr, hb_h, hb_l, 1024, 1024);
    gemm_mfma_k<128, 2, false><<<dim3(33, 8), 256, 0, stream>>>(
        hb_h, hb_l, whid1_h, whid1_l, b_hid + HH, hb_h, hb_l, nullptr, hc_h, hc_l, 1024, 1024);
    gemm_mfma_k<64, 1, false><<<dim3(66, 4), 256, 0, stream>>>(
        hc_h, hc_l, wout_h, wout_l, b_out, nullptr, nullptr, nullptr, r_h, r_l, 1024, 512);
    // fused q/k/v projection -> [BT][1536] hi/lo
    gemm_mfma_k<64, 3, false><<<dim3(66, 12), 256, 0, stream>>>(
        r_h, r_l, wqkv_h, wqkv_l, bqkv, nullptr, nullptr, nullptr, qkv_h, qkv_l, 512, QKV_N);
    // flash sliding-window attention
    swa_flash_k<<<dim3(TT / 64, NHH, BB), 256, 0, stream>>>(qkv_h, qkv_l, ob_h, ob_l);
    // out = (ob @ wo + bo)[t >= M]
    gemm_mfma_k<64, 0, true><<<dim3(66, 4), 256, 0, stream>>>(
        ob_h, ob_l, wo_h, wo_l, bo, nullptr, nullptr, out, nullptr, nullptr, 512, 512);
}

// Round 4
// 320.651 us; speedup vs baseline: 3.0698x; 1.0117x over previous
//
#include <hip/hip_runtime.h>
#include <math.h>
#include <stdint.h>

#define BB 2
#define SS 2048
#define DD 512
#define HH 1024
#define MMETA 64
#define KCONV 4
#define NHH 8
#define DHH 64
#define WINN 256
#define TT (MMETA + SS)     // 2112
#define BT (BB * TT)        // 4224
#define QKV_N 1536

typedef __attribute__((ext_vector_type(8))) short short8v;   // 8 bf16 = 4 VGPR
typedef __attribute__((ext_vector_type(4))) float f32x4;

__device__ __forceinline__ unsigned short f2bf(float f) {
    union { float f; unsigned u; } c; c.f = f;
    unsigned u = c.u;
    unsigned r = (u + 0x7fffu + ((u >> 16) & 1u)) >> 16;   // RNE
    return (unsigned short)r;
}
__device__ __forceinline__ float bf2f(unsigned short h) {
    union { unsigned u; float f; } c; c.u = ((unsigned)h) << 16;
    return c.f;
}

__device__ __forceinline__ void gload_lds16(const void* g, void* l) {
    __builtin_amdgcn_global_load_lds(
        (const __attribute__((address_space(1))) unsigned int*)g,
        (__attribute__((address_space(3))) unsigned int*)l, 16, 0, 0);
}

// ---------------------------------------------------------------------------
// weight transpose + split:  W [K][N] fp32  ->  Wh/Wl [N][K] bf16
// ---------------------------------------------------------------------------
__global__ __launch_bounds__(256) void wsplit_k(
    const float* __restrict__ W, unsigned short* __restrict__ Wh,
    unsigned short* __restrict__ Wl, int K, int N)
{
    __shared__ float tile[64][65];
    const int tid = threadIdx.x;
    const int k0 = blockIdx.x * 64, n0 = blockIdx.y * 64;
    #pragma unroll
    for (int i = 0; i < 16; ++i) {
        int lin = i * 256 + tid;
        int kr = lin >> 6, nc = lin & 63;
        tile[kr][nc] = W[(size_t)(k0 + kr) * N + n0 + nc];
    }
    __syncthreads();
    #pragma unroll
    for (int i = 0; i < 16; ++i) {
        int lin = i * 256 + tid;
        int nr = lin >> 6, kc = lin & 63;
        float v = tile[kc][nr];
        unsigned short hi = f2bf(v);
        size_t idx = (size_t)(n0 + nr) * K + k0 + kc;
        Wh[idx] = hi;
        Wl[idx] = f2bf(v - bf2f(hi));
    }
}

// ---------------------------------------------------------------------------
// concat q/k/v biases into one [1536] buffer
// ---------------------------------------------------------------------------
__global__ __launch_bounds__(256) void bias_concat_k(
    const float* __restrict__ bq, const float* __restrict__ bk,
    const float* __restrict__ bv, float* __restrict__ o)
{
    int i = blockIdx.x * 256 + threadIdx.x;
    if (i >= QKV_N) return;
    float v;
    if (i < 512) v = bq[i];
    else if (i < 1024) v = bk[i - 512];
    else v = bv[i - 1024];
    o[i] = v;
}

// ---------------------------------------------------------------------------
// build xm = concat(meta, x) -> hi/lo bf16 [BT][D]
// ---------------------------------------------------------------------------
__global__ __launch_bounds__(256) void build_xm_k(
    const float* __restrict__ x, const float* __restrict__ meta,
    unsigned short* __restrict__ xh, unsigned short* __restrict__ xl)
{
    int idx = blockIdx.x * 256 + threadIdx.x;   // float4 index over BT*128
    if (idx >= BT * 128) return;
    int row = idx >> 7, c4 = idx & 127;
    int b = row >= TT;
    int t = row - b * TT;
    float4 v = (t < MMETA) ? ((const float4*)(meta + (size_t)t * DD))[c4]
                           : ((const float4*)(x + ((size_t)b * SS + (t - MMETA)) * DD))[c4];
    ushort4 h, lo;
    h.x = f2bf(v.x); lo.x = f2bf(v.x - bf2f(h.x));
    h.y = f2bf(v.y); lo.y = f2bf(v.y - bf2f(h.y));
    h.z = f2bf(v.z); lo.z = f2bf(v.z - bf2f(h.z));
    h.w = f2bf(v.w); lo.w = f2bf(v.w - bf2f(h.w));
    ((ushort4*)xh)[idx] = h;
    ((ushort4*)xl)[idx] = lo;
}

// ---------------------------------------------------------------------------
// bf16x3 MFMA GEMM:  C = epi( A @ W^T + bias [, res] )
//   EPI: 0 bias->fp32; 1 silu->hi/lo; 2 res+silu->hi/lo; 3 bias->hi/lo;
//        4 bias->hi/lo for cols<1024, transposed vt write for cols>=1024
// ---------------------------------------------------------------------------
template<int BM, int EPI, bool DROPMETA>
__global__ __launch_bounds__(256, 2) void gemm_mfma_k(
    const unsigned short* __restrict__ Ah, const unsigned short* __restrict__ Al,
    const unsigned short* __restrict__ Wh, const unsigned short* __restrict__ Wl,
    const float* __restrict__ bias,
    const unsigned short* __restrict__ resh, const unsigned short* __restrict__ resl,
    float* __restrict__ outf, unsigned short* __restrict__ outh,
    unsigned short* __restrict__ outl,
    unsigned short* __restrict__ vth, unsigned short* __restrict__ vtl,
    int K, int N)
{
    static_assert(BM == 64 || BM == 128, "");
    constexpr int MF = BM / 32;
    constexpr int ABYTES = BM * 64;      // A tile bytes (BM x 32 bf16)
    constexpr int BBYTES = 128 * 64;     // B tile bytes
    constexpr int BUFB = 2 * ABYTES + 2 * BBYTES;
    __shared__ short8v smem_v[(2 * BUFB) / 16];
    char* smem = (char*)smem_v;

    const int tid = threadIdx.x;
    const int l = tid & 63, wid = tid >> 6;
    const int wm = wid >> 1, wn = wid & 1;
    const int lr = l & 15, lg = l >> 4;
    const int row0 = blockIdx.x * BM;
    const int n0 = blockIdx.y * 128;

    const char* Ahg0 = (const char*)Ah + (size_t)row0 * K * 2;
    const char* Alg0 = (const char*)Al + (size_t)row0 * K * 2;
    const char* Whg  = (const char*)Wh + (size_t)n0 * K * 2;
    const char* Wlg  = (const char*)Wl + (size_t)n0 * K * 2;

    // conflict-free swizzle: sigma(r) = (r>>1)&3 over the 4 16B segs of a row
    int a_off[MF], b_off[4];
    #pragma unroll
    for (int mf = 0; mf < MF; ++mf) {
        int r = wm * (BM / 2) + mf * 16 + lr;
        a_off[mf] = r * 64 + ((lg * 16) ^ (((r >> 1) & 3) << 4));
    }
    #pragma unroll
    for (int nf = 0; nf < 4; ++nf) {
        int r = wn * 64 + nf * 16 + lr;
        b_off[nf] = r * 64 + ((lg * 16) ^ (((r >> 1) & 3) << 4));
    }

    f32x4 acc[MF][4];
    #pragma unroll
    for (int mf = 0; mf < MF; ++mf)
        #pragma unroll
        for (int nf = 0; nf < 4; ++nf) acc[mf][nf] = (f32x4){0.f, 0.f, 0.f, 0.f};

    const int NT = K / 32;

    auto stage = [&](int buf, int t) {
        char* lb = smem + buf * BUFB;
        const size_t kb = (size_t)t * 64;
        #pragma unroll
        for (int it = 0; it < ABYTES / 4096; ++it) {
            int off = (it * 256 + tid) * 16;
            int row = off >> 6;
            int sc = (off & 63) ^ (((row >> 1) & 3) << 4);
            size_t gb = (size_t)row * (K * 2) + kb + sc;
            gload_lds16(Ahg0 + gb, lb + off);
            gload_lds16(Alg0 + gb, lb + ABYTES + off);
        }
        #pragma unroll
        for (int it = 0; it < BBYTES / 4096; ++it) {
            int off = (it * 256 + tid) * 16;
            int row = off >> 6;
            int sc = (off & 63) ^ (((row >> 1) & 3) << 4);
            size_t gb = (size_t)row * (K * 2) + kb + sc;
            gload_lds16(Whg + gb, lb + 2 * ABYTES + off);
            gload_lds16(Wlg + gb, lb + 2 * ABYTES + BBYTES + off);
        }
    };

    stage(0, 0);
    __syncthreads();

    int cur = 0;
    for (int t = 0; t < NT; ++t) {
        if (t + 1 < NT) stage(cur ^ 1, t + 1);
        char* lb = smem + cur * BUFB;
        short8v ah[MF], al[MF], bh[4], bl[4];
        #pragma unroll
        for (int mf = 0; mf < MF; ++mf) {
            ah[mf] = *(const short8v*)(lb + a_off[mf]);
            al[mf] = *(const short8v*)(lb + ABYTES + a_off[mf]);
        }
        #pragma unroll
        for (int nf = 0; nf < 4; ++nf) {
            bh[nf] = *(const short8v*)(lb + 2 * ABYTES + b_off[nf]);
            bl[nf] = *(const short8v*)(lb + 2 * ABYTES + BBYTES + b_off[nf]);
        }
        #pragma unroll
        for (int mf = 0; mf < MF; ++mf)
            #pragma unroll
            for (int nf = 0; nf < 4; ++nf) {
                acc[mf][nf] = __builtin_amdgcn_mfma_f32_16x16x32_bf16(ah[mf], bh[nf], acc[mf][nf], 0, 0, 0);
                acc[mf][nf] = __builtin_amdgcn_mfma_f32_16x16x32_bf16(ah[mf], bl[nf], acc[mf][nf], 0, 0, 0);
                acc[mf][nf] = __builtin_amdgcn_mfma_f32_16x16x32_bf16(al[mf], bh[nf], acc[mf][nf], 0, 0, 0);
            }
        __syncthreads();
        cur ^= 1;
    }

    // epilogue: C/D layout col = lane&15, row = (lane>>4)*4 + reg
    #pragma unroll
    for (int mf = 0; mf < MF; ++mf) {
        #pragma unroll
        for (int nf = 0; nf < 4; ++nf) {
            int col = n0 + wn * 64 + nf * 16 + lr;
            float bv = bias[col];
            if (EPI == 4 && col >= 1024) {
                // transposed v write: vt[d][token], 4 consecutive tokens packed
                unsigned short hv[4], lv[4];
                #pragma unroll
                for (int j = 0; j < 4; ++j) {
                    float v = acc[mf][nf][j] + bv;
                    unsigned short hi = f2bf(v);
                    hv[j] = hi; lv[j] = f2bf(v - bf2f(hi));
                }
                int dg = col - 1024;
                size_t tok = (size_t)row0 + wm * (BM / 2) + mf * 16 + lg * 4;
                *(ushort4*)(vth + (size_t)dg * BT + tok) = *(ushort4*)hv;
                *(ushort4*)(vtl + (size_t)dg * BT + tok) = *(ushort4*)lv;
            } else {
                #pragma unroll
                for (int j = 0; j < 4; ++j) {
                    int row = row0 + wm * (BM / 2) + mf * 16 + lg * 4 + j;
                    float v = acc[mf][nf][j] + bv;
                    if (EPI == 1 || EPI == 2) v = v / (1.f + __expf(-v));
                    size_t idx = (size_t)row * N + col;
                    if (EPI == 2) v += bf2f(resh[idx]) + bf2f(resl[idx]);
                    if (EPI == 0) {
                        if (DROPMETA) {
                            int b = row >= TT;
                            int t2 = row - b * TT;
                            if (t2 >= MMETA)
                                outf[((size_t)b * SS + (t2 - MMETA)) * N + col] = v;
                        } else {
                            outf[idx] = v;
                        }
                    } else {
                        unsigned short hi = f2bf(v);
                        outh[idx] = hi;
                        outl[idx] = f2bf(v - bf2f(hi));
                    }
                }
            }
        }
    }
}

// ---------------------------------------------------------------------------
// causal depthwise conv (K=4) + L2 normalize; out as hi/lo bf16
// ---------------------------------------------------------------------------
__global__ __launch_bounds__(256) void conv_norm_k(
    const float* __restrict__ qlin, const float* __restrict__ convw,
    unsigned short* __restrict__ qh, unsigned short* __restrict__ ql)
{
    const int row = blockIdx.x;
    const int b = row >= TT;
    const int t = row - b * TT;
    const int tid = threadIdx.x;

    float vals[2];
    float ss = 0.f;
    #pragma unroll
    for (int e = 0; e < 2; ++e) {
        int d = tid + e * 256;
        float acc = 0.f;
        #pragma unroll
        for (int k = 0; k < KCONV; ++k) {
            int tt = t - (KCONV - 1) + k;
            if (tt >= 0)
                acc += qlin[((size_t)b * TT + tt) * DD + d] * convw[k * DD + d];
        }
        vals[e] = acc;
        ss += acc * acc;
    }
    #pragma unroll
    for (int off = 32; off > 0; off >>= 1)
        ss += __shfl_xor(ss, off);
    __shared__ float red[4];
    if ((tid & 63) == 0) red[tid >> 6] = ss;
    __syncthreads();
    float total = red[0] + red[1] + red[2] + red[3];
    float inv = 1.f / fmaxf(sqrtf(total), 1e-12f);
    #pragma unroll
    for (int e = 0; e < 2; ++e) {
        int d = tid + e * 256;
        float v = vals[e] * inv;
        unsigned short hi = f2bf(v);
        qh[(size_t)row * DD + d] = hi;
        ql[(size_t)row * DD + d] = f2bf(v - bf2f(hi));
    }
}

// ---------------------------------------------------------------------------
// Flash sliding-window attention, MFMA, V^T staged from global.
//   Block: 64 queries x 1 head x 1 batch, 4 waves (wave = 16 query rows).
// ---------------------------------------------------------------------------
__global__ __launch_bounds__(256, 2) void swa_flash_k(
    const unsigned short* __restrict__ qkvh, const unsigned short* __restrict__ qkvl,
    const unsigned short* __restrict__ vth, const unsigned short* __restrict__ vtl,
    unsigned short* __restrict__ oh, unsigned short* __restrict__ ol)
{
    // LDS: Kh 8192 | Kl 8192 | Vh 8192 | Vl 8192 | P 4x2304
    __shared__ short8v lds_v[41984 / 16];
    char* lds = (char*)lds_v;
    char* Kh_lds = lds;
    char* Kl_lds = lds + 8192;
    char* Vh_lds = lds + 16384;
    char* Vl_lds = lds + 24576;
    char* P_lds  = lds + 32768;

    const int tid = threadIdx.x;
    const int lane = tid & 63, w = tid >> 6;
    const int l15 = lane & 15, lg = lane >> 4;
    const int q0 = blockIdx.x * 64;
    const int h = blockIdx.y, b = blockIdx.z;
    const int rowbase = b * TT;

    // Q fragments in registers (A-frag: row = lane&15, k = lg*8..+7)
    const int qrow = rowbase + q0 + w * 16 + l15;
    short8v qhf[2], qlf[2];
    #pragma unroll
    for (int kh = 0; kh < 2; ++kh) {
        size_t off = (size_t)qrow * QKV_N + h * 64 + kh * 32 + lg * 8;
        qhf[kh] = *(const short8v*)(qkvh + off);
        qlf[kh] = *(const short8v*)(qkvl + off);
    }

    f32x4 o_acc[4];
    #pragma unroll
    for (int td = 0; td < 4; ++td) o_acc[td] = (f32x4){0.f, 0.f, 0.f, 0.f};
    float m_r[4], l_r[4];
    #pragma unroll
    for (int r = 0; r < 4; ++r) { m_r[r] = -1e30f; l_r[r] = 0.f; }

    char* Pw = P_lds + w * 2304;   // per-wave [16][72] bf16

    for (int kt = 0; kt < 5; ++kt) {
        const int kst = q0 - 256 + kt * 64;
        if (kst + 64 <= 0) continue;    // note: staged tiles always have kst >= 0
        __syncthreads();
        // --- stage K rows (hi/lo): K[key][d], 128B rows, sigma = key&7 ---
        #pragma unroll
        for (int it = 0; it < 2; ++it) {
            int lin = it * 256 + tid;
            int r = lin >> 3, seg = lin & 7;
            int colb = (seg * 16) ^ ((r & 7) << 4);
            size_t gb = ((size_t)(rowbase + kst + r) * QKV_N + 512 + h * 64) * 2 + colb;
            gload_lds16((const char*)qkvh + gb, Kh_lds + lin * 16);
            gload_lds16((const char*)qkvl + gb, Kl_lds + lin * 16);
        }
        // --- stage V^T rows (hi/lo): vt[d][token], 128B rows, sigma = d&7 ---
        #pragma unroll
        for (int it = 0; it < 2; ++it) {
            int lin = it * 256 + tid;
            int dd = lin >> 3, seg = lin & 7;
            int colb = (seg * 16) ^ ((dd & 7) << 4);
            size_t gb = ((size_t)(h * 64 + dd) * BT + rowbase + kst) * 2 + colb;
            gload_lds16((const char*)vth + gb, Vh_lds + lin * 16);
            gload_lds16((const char*)vtl + gb, Vl_lds + lin * 16);
        }
        __syncthreads();

        // --- S = Q K^T (bf16x3) ---
        f32x4 s_fr[4];
        #pragma unroll
        for (int tj = 0; tj < 4; ++tj) s_fr[tj] = (f32x4){0.f, 0.f, 0.f, 0.f};
        #pragma unroll
        for (int tj = 0; tj < 4; ++tj) {
            int j = tj * 16 + l15;
            #pragma unroll
            for (int kh = 0; kh < 2; ++kh) {
                int colb = (kh * 64 + lg * 16) ^ ((j & 7) << 4);
                short8v kbh = *(const short8v*)(Kh_lds + j * 128 + colb);
                short8v kbl = *(const short8v*)(Kl_lds + j * 128 + colb);
                s_fr[tj] = __builtin_amdgcn_mfma_f32_16x16x32_bf16(qhf[kh], kbh, s_fr[tj], 0, 0, 0);
                s_fr[tj] = __builtin_amdgcn_mfma_f32_16x16x32_bf16(qhf[kh], kbl, s_fr[tj], 0, 0, 0);
                s_fr[tj] = __builtin_amdgcn_mfma_f32_16x16x32_bf16(qlf[kh], kbh, s_fr[tj], 0, 0, 0);
            }
        }
        // --- mask + scale ---
        #pragma unroll
        for (int tj = 0; tj < 4; ++tj) {
            int j = kst + tj * 16 + l15;
            #pragma unroll
            for (int r = 0; r < 4; ++r) {
                int i = q0 + w * 16 + lg * 4 + r;
                bool valid = (j <= i) && (i - j < WINN);
                s_fr[tj][r] = valid ? s_fr[tj][r] * 0.125f : -1e30f;
            }
        }
        // --- online softmax update ---
        float mx[4];
        #pragma unroll
        for (int r = 0; r < 4; ++r) {
            mx[r] = fmaxf(fmaxf(s_fr[0][r], s_fr[1][r]), fmaxf(s_fr[2][r], s_fr[3][r]));
            #pragma unroll
            for (int msk = 1; msk <= 8; msk <<= 1)
                mx[r] = fmaxf(mx[r], __shfl_xor(mx[r], msk));
            float mn = fmaxf(m_r[r], mx[r]);
            float sc = __expf(m_r[r] - mn);
            m_r[r] = mn;
            l_r[r] *= sc;
            #pragma unroll
            for (int td = 0; td < 4; ++td) o_acc[td][r] *= sc;
        }
        float rs[4] = {0.f, 0.f, 0.f, 0.f};
        #pragma unroll
        for (int tj = 0; tj < 4; ++tj) {
            #pragma unroll
            for (int r = 0; r < 4; ++r) {
                float p = __expf(s_fr[tj][r] - m_r[r]);
                rs[r] += p;
                ((unsigned short*)Pw)[(lg * 4 + r) * 72 + tj * 16 + l15] = f2bf(p);
            }
        }
        #pragma unroll
        for (int r = 0; r < 4; ++r) {
            #pragma unroll
            for (int msk = 1; msk <= 8; msk <<= 1)
                rs[r] += __shfl_xor(rs[r], msk);
            l_r[r] += rs[r];
        }
        // --- PV: O += P @ V  (P bf16 from LDS, V^T hi/lo from LDS) ---
        short8v pa[2];
        #pragma unroll
        for (int jh = 0; jh < 2; ++jh)
            pa[jh] = *(const short8v*)(Pw + l15 * 144 + jh * 64 + lg * 16);
        #pragma unroll
        for (int td = 0; td < 4; ++td) {
            int drow = td * 16 + l15;
            #pragma unroll
            for (int jh = 0; jh < 2; ++jh) {
                int colb = (jh * 64 + lg * 16) ^ ((drow & 7) << 4);
                short8v vfh = *(const short8v*)(Vh_lds + drow * 128 + colb);
                short8v vfl = *(const short8v*)(Vl_lds + drow * 128 + colb);
                o_acc[td] = __builtin_amdgcn_mfma_f32_16x16x32_bf16(pa[jh], vfh, o_acc[td], 0, 0, 0);
                o_acc[td] = __builtin_amdgcn_mfma_f32_16x16x32_bf16(pa[jh], vfl, o_acc[td], 0, 0, 0);
            }
        }
    }

    // --- epilogue ---
    #pragma unroll
    for (int r = 0; r < 4; ++r) {
        float inv = 1.f / l_r[r];
        int row = rowbase + q0 + w * 16 + lg * 4 + r;
        #pragma unroll
        for (int td = 0; td < 4; ++td) {
            float v = o_acc[td][r] * inv;
            size_t idx = (size_t)row * DD + h * 64 + td * 16 + l15;
            unsigned short hi = f2bf(v);
            oh[idx] = hi;
            ol[idx] = f2bf(v - bf2f(hi));
        }
    }
}

// ---------------------------------------------------------------------------
// Launch
// ---------------------------------------------------------------------------
extern "C" void kernel_launch(void* const* d_in, const int* in_sizes, int n_in,
                              void* d_out, int out_size, void* d_ws, size_t ws_size,
                              hipStream_t stream)
{
    const float* x       = (const float*)d_in[0];
    const float* meta    = (const float*)d_in[1];
    const float* qp_w    = (const float*)d_in[2];
    const float* qp_b    = (const float*)d_in[3];
    const float* qp_conv = (const float*)d_in[4];
    const float* w_in    = (const float*)d_in[5];
    const float* b_in    = (const float*)d_in[6];
    const float* w_hid   = (const float*)d_in[7];
    const float* b_hid   = (const float*)d_in[8];
    const float* w_out   = (const float*)d_in[9];
    const float* b_out   = (const float*)d_in[10];
    const float* wq      = (const float*)d_in[11];
    const float* bq      = (const float*)d_in[12];
    const float* wk      = (const float*)d_in[13];
    const float* bk      = (const float*)d_in[14];
    const float* wv      = (const float*)d_in[15];
    const float* bv      = (const float*)d_in[16];
    const float* wo      = (const float*)d_in[17];
    const float* bo      = (const float*)d_in[18];
    float* out = (float*)d_out;

    typedef unsigned short us;
    char* p = (char*)d_ws;
    auto alloc = [&](size_t n) { char* r = p; p += (n + 255) & ~(size_t)255; return r; };

    // split weights (hi/lo, transposed [N][K])
    us* wqp_h   = (us*)alloc(512 * 512 * 2);   us* wqp_l   = (us*)alloc(512 * 512 * 2);
    us* win_h   = (us*)alloc(512 * 1024 * 2);  us* win_l   = (us*)alloc(512 * 1024 * 2);
    us* whid0_h = (us*)alloc(1024 * 1024 * 2); us* whid0_l = (us*)alloc(1024 * 1024 * 2);
    us* whid1_h = (us*)alloc(1024 * 1024 * 2); us* whid1_l = (us*)alloc(1024 * 1024 * 2);
    us* wout_h  = (us*)alloc(1024 * 512 * 2);  us* wout_l  = (us*)alloc(1024 * 512 * 2);
    us* wqkv_h  = (us*)alloc((size_t)QKV_N * 512 * 2);
    us* wqkv_l  = (us*)alloc((size_t)QKV_N * 512 * 2);
    us* wo_h    = (us*)alloc(512 * 512 * 2);   us* wo_l    = (us*)alloc(512 * 512 * 2);
    float* bqkv = (float*)alloc(QKV_N * 4);

    const size_t HALF = (size_t)BT * 512 * 2;   // 4.3 MB
    char* RA = alloc(2 * HALF);   // xm hi/lo  -> later ob hi/lo
    char* RB = alloc(2 * HALF);   // qlin fp32
    char* RC = alloc(2 * HALF);   // qn hi/lo -> r hi/lo
    char* RD = alloc(6 * HALF);   // ha hi/lo -> hc hi/lo -> qkv hi/lo (q,k only)
    char* RE = alloc(4 * HALF);   // hb hi/lo -> vt hi/lo ([512][BT] each)

    us* xm_h = (us*)RA;   us* xm_l = (us*)(RA + HALF);
    float* qlin = (float*)RB;
    us* qn_h = (us*)RC;   us* qn_l = (us*)(RC + HALF);
    us* ha_h = (us*)RD;   us* ha_l = (us*)(RD + 2 * HALF);
    us* hb_h = (us*)RE;   us* hb_l = (us*)(RE + 2 * HALF);
    us* hc_h = ha_h;      us* hc_l = ha_l;
    us* r_h  = qn_h;      us* r_l  = qn_l;
    us* qkv_h = (us*)RD;  us* qkv_l = (us*)(RD + 3 * HALF);
    us* vt_h  = (us*)RE;  us* vt_l  = (us*)(RE + HALF);
    us* ob_h = (us*)RA;   us* ob_l = (us*)(RA + HALF);

    // --- weight prep ---
    wsplit_k<<<dim3(8, 8),   256, 0, stream>>>(qp_w,  wqp_h,  wqp_l,  512, 512);
    wsplit_k<<<dim3(8, 16),  256, 0, stream>>>(w_in,  win_h,  win_l,  512, 1024);
    wsplit_k<<<dim3(16, 16), 256, 0, stream>>>(w_hid, whid0_h, whid0_l, 1024, 1024);
    wsplit_k<<<dim3(16, 16), 256, 0, stream>>>(w_hid + (size_t)1024 * 1024, whid1_h, whid1_l, 1024, 1024);
    wsplit_k<<<dim3(16, 8),  256, 0, stream>>>(w_out, wout_h, wout_l, 1024, 512);
    wsplit_k<<<dim3(8, 8),   256, 0, stream>>>(wq, wqkv_h,                 wqkv_l,                 512, 512);
    wsplit_k<<<dim3(8, 8),   256, 0, stream>>>(wk, wqkv_h + 512 * 512,     wqkv_l + 512 * 512,     512, 512);
    wsplit_k<<<dim3(8, 8),   256, 0, stream>>>(wv, wqkv_h + 2 * 512 * 512, wqkv_l + 2 * 512 * 512, 512, 512);
    wsplit_k<<<dim3(8, 8),   256, 0, stream>>>(wo, wo_h, wo_l, 512, 512);
    bias_concat_k<<<6, 256, 0, stream>>>(bq, bk, bv, bqkv);

    // --- pipeline ---
    build_xm_k<<<(BT * 128 + 255) / 256, 256, 0, stream>>>(x, meta, xm_h, xm_l);

    gemm_mfma_k<64, 0, false><<<dim3(66, 4), 256, 0, stream>>>(
        xm_h, xm_l, wqp_h, wqp_l, qp_b, nullptr, nullptr, qlin, nullptr, nullptr, nullptr, nullptr, 512, 512);
    conv_norm_k<<<BT, 256, 0, stream>>>(qlin, qp_conv, qn_h, qn_l);
    gemm_mfma_k<128, 1, false><<<dim3(33, 8), 256, 0, stream>>>(
        qn_h, qn_l, win_h, win_l, b_in, nullptr, nullptr, nullptr, ha_h, ha_l, nullptr, nullptr, 512, 1024);
    gemm_mfma_k<128, 2, false><<<dim3(33, 8), 256, 0, stream>>>(
        ha_h, ha_l, whid0_h, whid0_l, b_hid, ha_h, ha_l, nullptr, hb_h, hb_l, nullptr, nullptr, 1024, 1024);
    gemm_mfma_k<128, 2, false><<<dim3(33, 8), 256, 0, stream>>>(
        hb_h, hb_l, whid1_h, whid1_l, b_hid + HH, hb_h, hb_l, nullptr, hc_h, hc_l, nullptr, nullptr, 1024, 1024);
    gemm_mfma_k<64, 1, false><<<dim3(66, 4), 256, 0, stream>>>(
        hc_h, hc_l, wout_h, wout_l, b_out, nullptr, nullptr, nullptr, r_h, r_l, nullptr, nullptr, 1024, 512);
    // fused q/k/v projection -> q,k into qkv[BT][1536]; v transposed into vt[512][BT]
    gemm_mfma_k<64, 4, false><<<dim3(66, 12), 256, 0, stream>>>(
        r_h, r_l, wqkv_h, wqkv_l, bqkv, nullptr, nullptr, nullptr, qkv_h, qkv_l, vt_h, vt_l, 512, QKV_N);
    // flash sliding-window attention
    swa_flash_k<<<dim3(TT / 64, NHH, BB), 256, 0, stream>>>(qkv_h, qkv_l, vt_h, vt_l, ob_h, ob_l);
    // out = (ob @ wo + bo)[t >= M]
    gemm_mfma_k<64, 0, true><<<dim3(66, 4), 256, 0, stream>>>(
        ob_h, ob_l, wo_h, wo_l, bo, nullptr, nullptr, out, nullptr, nullptr, nullptr, nullptr, 512, 512);
}

// Round 5
// 269.429 us; speedup vs baseline: 3.6534x; 1.1901x over previous
//
#include <hip/hip_runtime.h>
#include <math.h>
#include <stdint.h>

#define BB 2
#define SS 2048
#define DD 512
#define HH 1024
#define MMETA 64
#define KCONV 4
#define NHH 8
#define DHH 64
#define WINN 256
#define TT (MMETA + SS)     // 2112
#define BT (BB * TT)        // 4224
#define QKV_N 1536

typedef __attribute__((ext_vector_type(8))) short short8v;   // 8 bf16 = 4 VGPR
typedef __attribute__((ext_vector_type(4))) float f32x4;

__device__ __forceinline__ unsigned short f2bf(float f) {
    union { float f; unsigned u; } c; c.f = f;
    unsigned u = c.u;
    unsigned r = (u + 0x7fffu + ((u >> 16) & 1u)) >> 16;   // RNE
    return (unsigned short)r;
}
__device__ __forceinline__ float bf2f(unsigned short h) {
    union { unsigned u; float f; } c; c.u = ((unsigned)h) << 16;
    return c.f;
}

__device__ __forceinline__ void gload_lds16(const void* g, void* l) {
    __builtin_amdgcn_global_load_lds(
        (const __attribute__((address_space(1))) unsigned int*)g,
        (__attribute__((address_space(3))) unsigned int*)l, 16, 0, 0);
}

// ---------------------------------------------------------------------------
// weight transpose + split:  W [K][N] fp32  ->  Wh/Wl [N][K] bf16
// ---------------------------------------------------------------------------
__global__ __launch_bounds__(256) void wsplit_k(
    const float* __restrict__ W, unsigned short* __restrict__ Wh,
    unsigned short* __restrict__ Wl, int K, int N)
{
    __shared__ float tile[64][65];
    const int tid = threadIdx.x;
    const int k0 = blockIdx.x * 64, n0 = blockIdx.y * 64;
    #pragma unroll
    for (int i = 0; i < 16; ++i) {
        int lin = i * 256 + tid;
        int kr = lin >> 6, nc = lin & 63;
        tile[kr][nc] = W[(size_t)(k0 + kr) * N + n0 + nc];
    }
    __syncthreads();
    #pragma unroll
    for (int i = 0; i < 16; ++i) {
        int lin = i * 256 + tid;
        int nr = lin >> 6, kc = lin & 63;
        float v = tile[kc][nr];
        unsigned short hi = f2bf(v);
        size_t idx = (size_t)(n0 + nr) * K + k0 + kc;
        Wh[idx] = hi;
        Wl[idx] = f2bf(v - bf2f(hi));
    }
}

// ---------------------------------------------------------------------------
// concat q/k/v biases into one [1536] buffer
// ---------------------------------------------------------------------------
__global__ __launch_bounds__(256) void bias_concat_k(
    const float* __restrict__ bq, const float* __restrict__ bk,
    const float* __restrict__ bv, float* __restrict__ o)
{
    int i = blockIdx.x * 256 + threadIdx.x;
    if (i >= QKV_N) return;
    float v;
    if (i < 512) v = bq[i];
    else if (i < 1024) v = bk[i - 512];
    else v = bv[i - 1024];
    o[i] = v;
}

// ---------------------------------------------------------------------------
// build xm = concat(meta, x) -> hi/lo bf16 [BT][D]
// ---------------------------------------------------------------------------
__global__ __launch_bounds__(256) void build_xm_k(
    const float* __restrict__ x, const float* __restrict__ meta,
    unsigned short* __restrict__ xh, unsigned short* __restrict__ xl)
{
    int idx = blockIdx.x * 256 + threadIdx.x;   // float4 index over BT*128
    if (idx >= BT * 128) return;
    int row = idx >> 7, c4 = idx & 127;
    int b = row >= TT;
    int t = row - b * TT;
    float4 v = (t < MMETA) ? ((const float4*)(meta + (size_t)t * DD))[c4]
                           : ((const float4*)(x + ((size_t)b * SS + (t - MMETA)) * DD))[c4];
    ushort4 h, lo;
    h.x = f2bf(v.x); lo.x = f2bf(v.x - bf2f(h.x));
    h.y = f2bf(v.y); lo.y = f2bf(v.y - bf2f(h.y));
    h.z = f2bf(v.z); lo.z = f2bf(v.z - bf2f(h.z));
    h.w = f2bf(v.w); lo.w = f2bf(v.w - bf2f(h.w));
    ((ushort4*)xh)[idx] = h;
    ((ushort4*)xl)[idx] = lo;
}

// ---------------------------------------------------------------------------
// bf16x3 MFMA GEMM:  C = epi( A @ W^T + bias [, res] )
//   BM=64 fixed; BN = 64 or 128; 1D grid of 66*GN blocks, XCD-chunk swizzled.
//   EPI: 0 bias->fp32; 1 silu->hi/lo; 2 res+silu->hi/lo; 3 bias->hi/lo;
//        4 bias->hi/lo for cols<1024, transposed vt write for cols>=1024
// ---------------------------------------------------------------------------
template<int BN, int GN, int EPI, bool DROPMETA>
__global__ __launch_bounds__(256, 4) void gemm_mfma_k(
    const unsigned short* __restrict__ Ah, const unsigned short* __restrict__ Al,
    const unsigned short* __restrict__ Wh, const unsigned short* __restrict__ Wl,
    const float* __restrict__ bias,
    const unsigned short* __restrict__ resh, const unsigned short* __restrict__ resl,
    float* __restrict__ outf, unsigned short* __restrict__ outh,
    unsigned short* __restrict__ outl,
    unsigned short* __restrict__ vth, unsigned short* __restrict__ vtl,
    int K, int N)
{
    constexpr int MF = 2;              // 2 row frags (wave covers 32 rows)
    constexpr int NF = BN / 32;        // col frags per wave (wave covers BN/2)
    constexpr int ABYTES = 64 * 64;    // 64 rows x 32 k x 2B
    constexpr int BBYTES = BN * 64;
    constexpr int BUFB = 2 * ABYTES + 2 * BBYTES;
    __shared__ short8v smem_v[(2 * BUFB) / 16];
    char* smem = (char*)smem_v;

    // XCD-chunk swizzle: nwg % 8 == 0 guaranteed by launcher
    constexpr int NWG = 66 * GN;
    const int orig = blockIdx.x;
    const int swz = (orig & 7) * (NWG >> 3) + (orig >> 3);
    const int row0 = (swz / GN) * 64;
    const int n0 = (swz % GN) * BN;

    const int tid = threadIdx.x;
    const int l = tid & 63, wid = tid >> 6;
    const int wm = wid >> 1, wn = wid & 1;
    const int lr = l & 15, lg = l >> 4;

    const char* Ahg0 = (const char*)Ah + (size_t)row0 * K * 2;
    const char* Alg0 = (const char*)Al + (size_t)row0 * K * 2;
    const char* Whg  = (const char*)Wh + (size_t)n0 * K * 2;
    const char* Wlg  = (const char*)Wl + (size_t)n0 * K * 2;

    // conflict-free swizzle: sigma(r) = (r>>1)&3 over the 4 16B segs of a row
    int a_off[MF], b_off[NF];
    #pragma unroll
    for (int mf = 0; mf < MF; ++mf) {
        int r = wm * 32 + mf * 16 + lr;
        a_off[mf] = r * 64 + ((lg * 16) ^ (((r >> 1) & 3) << 4));
    }
    #pragma unroll
    for (int nf = 0; nf < NF; ++nf) {
        int r = wn * (BN / 2) + nf * 16 + lr;
        b_off[nf] = r * 64 + ((lg * 16) ^ (((r >> 1) & 3) << 4));
    }

    f32x4 acc[MF][NF];
    #pragma unroll
    for (int mf = 0; mf < MF; ++mf)
        #pragma unroll
        for (int nf = 0; nf < NF; ++nf) acc[mf][nf] = (f32x4){0.f, 0.f, 0.f, 0.f};

    const int NT = K / 32;

    auto stage = [&](int buf, int t) {
        char* lb = smem + buf * BUFB;
        const size_t kb = (size_t)t * 64;
        {
            int off = tid * 16;
            int row = off >> 6;
            int sc = (off & 63) ^ (((row >> 1) & 3) << 4);
            size_t gb = (size_t)row * (K * 2) + kb + sc;
            gload_lds16(Ahg0 + gb, lb + off);
            gload_lds16(Alg0 + gb, lb + ABYTES + off);
        }
        #pragma unroll
        for (int it = 0; it < BBYTES / 4096; ++it) {
            int off = (it * 256 + tid) * 16;
            int row = off >> 6;
            int sc = (off & 63) ^ (((row >> 1) & 3) << 4);
            size_t gb = (size_t)row * (K * 2) + kb + sc;
            gload_lds16(Whg + gb, lb + 2 * ABYTES + off);
            gload_lds16(Wlg + gb, lb + 2 * ABYTES + BBYTES + off);
        }
    };

    stage(0, 0);
    __syncthreads();

    int cur = 0;
    for (int t = 0; t < NT; ++t) {
        if (t + 1 < NT) stage(cur ^ 1, t + 1);
        char* lb = smem + cur * BUFB;
        short8v ah[MF], al[MF], bh[NF], bl[NF];
        #pragma unroll
        for (int mf = 0; mf < MF; ++mf) {
            ah[mf] = *(const short8v*)(lb + a_off[mf]);
            al[mf] = *(const short8v*)(lb + ABYTES + a_off[mf]);
        }
        #pragma unroll
        for (int nf = 0; nf < NF; ++nf) {
            bh[nf] = *(const short8v*)(lb + 2 * ABYTES + b_off[nf]);
            bl[nf] = *(const short8v*)(lb + 2 * ABYTES + BBYTES + b_off[nf]);
        }
        #pragma unroll
        for (int mf = 0; mf < MF; ++mf)
            #pragma unroll
            for (int nf = 0; nf < NF; ++nf) {
                acc[mf][nf] = __builtin_amdgcn_mfma_f32_16x16x32_bf16(ah[mf], bh[nf], acc[mf][nf], 0, 0, 0);
                acc[mf][nf] = __builtin_amdgcn_mfma_f32_16x16x32_bf16(ah[mf], bl[nf], acc[mf][nf], 0, 0, 0);
                acc[mf][nf] = __builtin_amdgcn_mfma_f32_16x16x32_bf16(al[mf], bh[nf], acc[mf][nf], 0, 0, 0);
            }
        __syncthreads();
        cur ^= 1;
    }

    // epilogue: C/D layout col = lane&15, row = (lane>>4)*4 + reg
    #pragma unroll
    for (int mf = 0; mf < MF; ++mf) {
        #pragma unroll
        for (int nf = 0; nf < NF; ++nf) {
            int col = n0 + wn * (BN / 2) + nf * 16 + lr;
            float bv = bias[col];
            if (EPI == 4 && col >= 1024) {
                // transposed v write: vt[d][token], 4 consecutive tokens packed
                unsigned short hv[4], lv[4];
                #pragma unroll
                for (int j = 0; j < 4; ++j) {
                    float v = acc[mf][nf][j] + bv;
                    unsigned short hi = f2bf(v);
                    hv[j] = hi; lv[j] = f2bf(v - bf2f(hi));
                }
                int dg = col - 1024;
                size_t tok = (size_t)row0 + wm * 32 + mf * 16 + lg * 4;
                *(ushort4*)(vth + (size_t)dg * BT + tok) = *(ushort4*)hv;
                *(ushort4*)(vtl + (size_t)dg * BT + tok) = *(ushort4*)lv;
            } else {
                #pragma unroll
                for (int j = 0; j < 4; ++j) {
                    int row = row0 + wm * 32 + mf * 16 + lg * 4 + j;
                    float v = acc[mf][nf][j] + bv;
                    if (EPI == 1 || EPI == 2) v = v / (1.f + __expf(-v));
                    size_t idx = (size_t)row * N + col;
                    if (EPI == 2) v += bf2f(resh[idx]) + bf2f(resl[idx]);
                    if (EPI == 0) {
                        if (DROPMETA) {
                            int b = row >= TT;
                            int t2 = row - b * TT;
                            if (t2 >= MMETA)
                                outf[((size_t)b * SS + (t2 - MMETA)) * N + col] = v;
                        } else {
                            outf[idx] = v;
                        }
                    } else {
                        unsigned short hi = f2bf(v);
                        outh[idx] = hi;
                        outl[idx] = f2bf(v - bf2f(hi));
                    }
                }
            }
        }
    }
}

// ---------------------------------------------------------------------------
// causal depthwise conv (K=4) + L2 normalize; out as hi/lo bf16
// ---------------------------------------------------------------------------
__global__ __launch_bounds__(256) void conv_norm_k(
    const float* __restrict__ qlin, const float* __restrict__ convw,
    unsigned short* __restrict__ qh, unsigned short* __restrict__ ql)
{
    const int row = blockIdx.x;
    const int b = row >= TT;
    const int t = row - b * TT;
    const int tid = threadIdx.x;

    float vals[2];
    float ss = 0.f;
    #pragma unroll
    for (int e = 0; e < 2; ++e) {
        int d = tid + e * 256;
        float acc = 0.f;
        #pragma unroll
        for (int k = 0; k < KCONV; ++k) {
            int tt = t - (KCONV - 1) + k;
            if (tt >= 0)
                acc += qlin[((size_t)b * TT + tt) * DD + d] * convw[k * DD + d];
        }
        vals[e] = acc;
        ss += acc * acc;
    }
    #pragma unroll
    for (int off = 32; off > 0; off >>= 1)
        ss += __shfl_xor(ss, off);
    __shared__ float red[4];
    if ((tid & 63) == 0) red[tid >> 6] = ss;
    __syncthreads();
    float total = red[0] + red[1] + red[2] + red[3];
    float inv = 1.f / fmaxf(sqrtf(total), 1e-12f);
    #pragma unroll
    for (int e = 0; e < 2; ++e) {
        int d = tid + e * 256;
        float v = vals[e] * inv;
        unsigned short hi = f2bf(v);
        qh[(size_t)row * DD + d] = hi;
        ql[(size_t)row * DD + d] = f2bf(v - bf2f(hi));
    }
}

// ---------------------------------------------------------------------------
// Flash sliding-window attention, MFMA, V^T staged from global.
//   Block: 64 queries x 1 head x 1 batch, 4 waves (wave = 16 query rows).
// ---------------------------------------------------------------------------
__global__ __launch_bounds__(256, 2) void swa_flash_k(
    const unsigned short* __restrict__ qkvh, const unsigned short* __restrict__ qkvl,
    const unsigned short* __restrict__ vth, const unsigned short* __restrict__ vtl,
    unsigned short* __restrict__ oh, unsigned short* __restrict__ ol)
{
    // LDS: Kh 8192 | Kl 8192 | Vh 8192 | Vl 8192 | P 4x2304
    __shared__ short8v lds_v[41984 / 16];
    char* lds = (char*)lds_v;
    char* Kh_lds = lds;
    char* Kl_lds = lds + 8192;
    char* Vh_lds = lds + 16384;
    char* Vl_lds = lds + 24576;
    char* P_lds  = lds + 32768;

    const int tid = threadIdx.x;
    const int lane = tid & 63, w = tid >> 6;
    const int l15 = lane & 15, lg = lane >> 4;
    const int q0 = blockIdx.x * 64;
    const int h = blockIdx.y, b = blockIdx.z;
    const int rowbase = b * TT;

    // Q fragments in registers (A-frag: row = lane&15, k = lg*8..+7)
    const int qrow = rowbase + q0 + w * 16 + l15;
    short8v qhf[2], qlf[2];
    #pragma unroll
    for (int kh = 0; kh < 2; ++kh) {
        size_t off = (size_t)qrow * QKV_N + h * 64 + kh * 32 + lg * 8;
        qhf[kh] = *(const short8v*)(qkvh + off);
        qlf[kh] = *(const short8v*)(qkvl + off);
    }

    f32x4 o_acc[4];
    #pragma unroll
    for (int td = 0; td < 4; ++td) o_acc[td] = (f32x4){0.f, 0.f, 0.f, 0.f};
    float m_r[4], l_r[4];
    #pragma unroll
    for (int r = 0; r < 4; ++r) { m_r[r] = -1e30f; l_r[r] = 0.f; }

    char* Pw = P_lds + w * 2304;   // per-wave [16][72] bf16

    for (int kt = 0; kt < 5; ++kt) {
        const int kst = q0 - 256 + kt * 64;
        if (kst + 64 <= 0) continue;    // staged tiles always have kst >= 0
        __syncthreads();
        // --- stage K rows (hi/lo): K[key][d], 128B rows, sigma = key&7 ---
        #pragma unroll
        for (int it = 0; it < 2; ++it) {
            int lin = it * 256 + tid;
            int r = lin >> 3, seg = lin & 7;
            int colb = (seg * 16) ^ ((r & 7) << 4);
            size_t gb = ((size_t)(rowbase + kst + r) * QKV_N + 512 + h * 64) * 2 + colb;
            gload_lds16((const char*)qkvh + gb, Kh_lds + lin * 16);
            gload_lds16((const char*)qkvl + gb, Kl_lds + lin * 16);
        }
        // --- stage V^T rows (hi/lo): vt[d][token], 128B rows, sigma = d&7 ---
        #pragma unroll
        for (int it = 0; it < 2; ++it) {
            int lin = it * 256 + tid;
            int dd = lin >> 3, seg = lin & 7;
            int colb = (seg * 16) ^ ((dd & 7) << 4);
            size_t gb = ((size_t)(h * 64 + dd) * BT + rowbase + kst) * 2 + colb;
            gload_lds16((const char*)vth + gb, Vh_lds + lin * 16);
            gload_lds16((const char*)vtl + gb, Vl_lds + lin * 16);
        }
        __syncthreads();

        // --- S = Q K^T (bf16x3) ---
        f32x4 s_fr[4];
        #pragma unroll
        for (int tj = 0; tj < 4; ++tj) s_fr[tj] = (f32x4){0.f, 0.f, 0.f, 0.f};
        #pragma unroll
        for (int tj = 0; tj < 4; ++tj) {
            int j = tj * 16 + l15;
            #pragma unroll
            for (int kh = 0; kh < 2; ++kh) {
                int colb = (kh * 64 + lg * 16) ^ ((j & 7) << 4);
                short8v kbh = *(const short8v*)(Kh_lds + j * 128 + colb);
                short8v kbl = *(const short8v*)(Kl_lds + j * 128 + colb);
                s_fr[tj] = __builtin_amdgcn_mfma_f32_16x16x32_bf16(qhf[kh], kbh, s_fr[tj], 0, 0, 0);
                s_fr[tj] = __builtin_amdgcn_mfma_f32_16x16x32_bf16(qhf[kh], kbl, s_fr[tj], 0, 0, 0);
                s_fr[tj] = __builtin_amdgcn_mfma_f32_16x16x32_bf16(qlf[kh], kbh, s_fr[tj], 0, 0, 0);
            }
        }
        // --- mask + scale ---
        #pragma unroll
        for (int tj = 0; tj < 4; ++tj) {
            int j = kst + tj * 16 + l15;
            #pragma unroll
            for (int r = 0; r < 4; ++r) {
                int i = q0 + w * 16 + lg * 4 + r;
                bool valid = (j <= i) && (i - j < WINN);
                s_fr[tj][r] = valid ? s_fr[tj][r] * 0.125f : -1e30f;
            }
        }
        // --- online softmax update ---
        float mx[4];
        #pragma unroll
        for (int r = 0; r < 4; ++r) {
            mx[r] = fmaxf(fmaxf(s_fr[0][r], s_fr[1][r]), fmaxf(s_fr[2][r], s_fr[3][r]));
            #pragma unroll
            for (int msk = 1; msk <= 8; msk <<= 1)
                mx[r] = fmaxf(mx[r], __shfl_xor(mx[r], msk));
            float mn = fmaxf(m_r[r], mx[r]);
            float sc = __expf(m_r[r] - mn);
            m_r[r] = mn;
            l_r[r] *= sc;
            #pragma unroll
            for (int td = 0; td < 4; ++td) o_acc[td][r] *= sc;
        }
        float rs[4] = {0.f, 0.f, 0.f, 0.f};
        #pragma unroll
        for (int tj = 0; tj < 4; ++tj) {
            #pragma unroll
            for (int r = 0; r < 4; ++r) {
                float p = __expf(s_fr[tj][r] - m_r[r]);
                rs[r] += p;
                ((unsigned short*)Pw)[(lg * 4 + r) * 72 + tj * 16 + l15] = f2bf(p);
            }
        }
        #pragma unroll
        for (int r = 0; r < 4; ++r) {
            #pragma unroll
            for (int msk = 1; msk <= 8; msk <<= 1)
                rs[r] += __shfl_xor(rs[r], msk);
            l_r[r] += rs[r];
        }
        // --- PV: O += P @ V  (P bf16 from LDS, V^T hi/lo from LDS) ---
        short8v pa[2];
        #pragma unroll
        for (int jh = 0; jh < 2; ++jh)
            pa[jh] = *(const short8v*)(Pw + l15 * 144 + jh * 64 + lg * 16);
        #pragma unroll
        for (int td = 0; td < 4; ++td) {
            int drow = td * 16 + l15;
            #pragma unroll
            for (int jh = 0; jh < 2; ++jh) {
                int colb = (jh * 64 + lg * 16) ^ ((drow & 7) << 4);
                short8v vfh = *(const short8v*)(Vh_lds + drow * 128 + colb);
                short8v vfl = *(const short8v*)(Vl_lds + drow * 128 + colb);
                o_acc[td] = __builtin_amdgcn_mfma_f32_16x16x32_bf16(pa[jh], vfh, o_acc[td], 0, 0, 0);
                o_acc[td] = __builtin_amdgcn_mfma_f32_16x16x32_bf16(pa[jh], vfl, o_acc[td], 0, 0, 0);
            }
        }
    }

    // --- epilogue ---
    #pragma unroll
    for (int r = 0; r < 4; ++r) {
        float inv = 1.f / l_r[r];
        int row = rowbase + q0 + w * 16 + lg * 4 + r;
        #pragma unroll
        for (int td = 0; td < 4; ++td) {
            float v = o_acc[td][r] * inv;
            size_t idx = (size_t)row * DD + h * 64 + td * 16 + l15;
            unsigned short hi = f2bf(v);
            oh[idx] = hi;
            ol[idx] = f2bf(v - bf2f(hi));
        }
    }
}

// ---------------------------------------------------------------------------
// Launch
// ---------------------------------------------------------------------------
extern "C" void kernel_launch(void* const* d_in, const int* in_sizes, int n_in,
                              void* d_out, int out_size, void* d_ws, size_t ws_size,
                              hipStream_t stream)
{
    const float* x       = (const float*)d_in[0];
    const float* meta    = (const float*)d_in[1];
    const float* qp_w    = (const float*)d_in[2];
    const float* qp_b    = (const float*)d_in[3];
    const float* qp_conv = (const float*)d_in[4];
    const float* w_in    = (const float*)d_in[5];
    const float* b_in    = (const float*)d_in[6];
    const float* w_hid   = (const float*)d_in[7];
    const float* b_hid   = (const float*)d_in[8];
    const float* w_out   = (const float*)d_in[9];
    const float* b_out   = (const float*)d_in[10];
    const float* wq      = (const float*)d_in[11];
    const float* bq      = (const float*)d_in[12];
    const float* wk      = (const float*)d_in[13];
    const float* bk      = (const float*)d_in[14];
    const float* wv      = (const float*)d_in[15];
    const float* bv      = (const float*)d_in[16];
    const float* wo      = (const float*)d_in[17];
    const float* bo      = (const float*)d_in[18];
    float* out = (float*)d_out;

    typedef unsigned short us;
    char* p = (char*)d_ws;
    auto alloc = [&](size_t n) { char* r = p; p += (n + 255) & ~(size_t)255; return r; };

    // split weights (hi/lo, transposed [N][K])
    us* wqp_h   = (us*)alloc(512 * 512 * 2);   us* wqp_l   = (us*)alloc(512 * 512 * 2);
    us* win_h   = (us*)alloc(512 * 1024 * 2);  us* win_l   = (us*)alloc(512 * 1024 * 2);
    us* whid0_h = (us*)alloc(1024 * 1024 * 2); us* whid0_l = (us*)alloc(1024 * 1024 * 2);
    us* whid1_h = (us*)alloc(1024 * 1024 * 2); us* whid1_l = (us*)alloc(1024 * 1024 * 2);
    us* wout_h  = (us*)alloc(1024 * 512 * 2);  us* wout_l  = (us*)alloc(1024 * 512 * 2);
    us* wqkv_h  = (us*)alloc((size_t)QKV_N * 512 * 2);
    us* wqkv_l  = (us*)alloc((size_t)QKV_N * 512 * 2);
    us* wo_h    = (us*)alloc(512 * 512 * 2);   us* wo_l    = (us*)alloc(512 * 512 * 2);
    float* bqkv = (float*)alloc(QKV_N * 4);

    const size_t HALF = (size_t)BT * 512 * 2;   // 4.3 MB
    char* RA = alloc(2 * HALF);   // xm hi/lo  -> later ob hi/lo
    char* RB = alloc(2 * HALF);   // qlin fp32
    char* RC = alloc(2 * HALF);   // qn hi/lo -> r hi/lo
    char* RD = alloc(6 * HALF);   // ha hi/lo -> hc hi/lo -> qkv hi/lo (q,k only)
    char* RE = alloc(4 * HALF);   // hb hi/lo -> vt hi/lo ([512][BT] each)

    us* xm_h = (us*)RA;   us* xm_l = (us*)(RA + HALF);
    float* qlin = (float*)RB;
    us* qn_h = (us*)RC;   us* qn_l = (us*)(RC + HALF);
    us* ha_h = (us*)RD;   us* ha_l = (us*)(RD + 2 * HALF);
    us* hb_h = (us*)RE;   us* hb_l = (us*)(RE + 2 * HALF);
    us* hc_h = ha_h;      us* hc_l = ha_l;
    us* r_h  = qn_h;      us* r_l  = qn_l;
    us* qkv_h = (us*)RD;  us* qkv_l = (us*)(RD + 3 * HALF);
    us* vt_h  = (us*)RE;  us* vt_l  = (us*)(RE + HALF);
    us* ob_h = (us*)RA;   us* ob_l = (us*)(RA + HALF);

    // --- weight prep ---
    wsplit_k<<<dim3(8, 8),   256, 0, stream>>>(qp_w,  wqp_h,  wqp_l,  512, 512);
    wsplit_k<<<dim3(8, 16),  256, 0, stream>>>(w_in,  win_h,  win_l,  512, 1024);
    wsplit_k<<<dim3(16, 16), 256, 0, stream>>>(w_hid, whid0_h, whid0_l, 1024, 1024);
    wsplit_k<<<dim3(16, 16), 256, 0, stream>>>(w_hid + (size_t)1024 * 1024, whid1_h, whid1_l, 1024, 1024);
    wsplit_k<<<dim3(16, 8),  256, 0, stream>>>(w_out, wout_h, wout_l, 1024, 512);
    wsplit_k<<<dim3(8, 8),   256, 0, stream>>>(wq, wqkv_h,                 wqkv_l,                 512, 512);
    wsplit_k<<<dim3(8, 8),   256, 0, stream>>>(wk, wqkv_h + 512 * 512,     wqkv_l + 512 * 512,     512, 512);
    wsplit_k<<<dim3(8, 8),   256, 0, stream>>>(wv, wqkv_h + 2 * 512 * 512, wqkv_l + 2 * 512 * 512, 512, 512);
    wsplit_k<<<dim3(8, 8),   256, 0, stream>>>(wo, wo_h, wo_l, 512, 512);
    bias_concat_k<<<6, 256, 0, stream>>>(bq, bk, bv, bqkv);

    // --- pipeline ---
    build_xm_k<<<(BT * 128 + 255) / 256, 256, 0, stream>>>(x, meta, xm_h, xm_l);

    // qlin = xm @ qp_w + b (fp32 out): N=512, BN=64, grid 528
    gemm_mfma_k<64, 8, 0, false><<<528, 256, 0, stream>>>(
        xm_h, xm_l, wqp_h, wqp_l, qp_b, nullptr, nullptr, qlin, nullptr, nullptr, nullptr, nullptr, 512, 512);
    conv_norm_k<<<BT, 256, 0, stream>>>(qlin, qp_conv, qn_h, qn_l);
    // ha = silu(qn @ w_in + b_in): N=1024, BN=128, grid 528
    gemm_mfma_k<128, 8, 1, false><<<528, 256, 0, stream>>>(
        qn_h, qn_l, win_h, win_l, b_in, nullptr, nullptr, nullptr, ha_h, ha_l, nullptr, nullptr, 512, 1024);
    gemm_mfma_k<128, 8, 2, false><<<528, 256, 0, stream>>>(
        ha_h, ha_l, whid0_h, whid0_l, b_hid, ha_h, ha_l, nullptr, hb_h, hb_l, nullptr, nullptr, 1024, 1024);
    gemm_mfma_k<128, 8, 2, false><<<528, 256, 0, stream>>>(
        hb_h, hb_l, whid1_h, whid1_l, b_hid + HH, hb_h, hb_l, nullptr, hc_h, hc_l, nullptr, nullptr, 1024, 1024);
    // r = silu(hc @ w_out + b_out): N=512, BN=64, grid 528
    gemm_mfma_k<64, 8, 1, false><<<528, 256, 0, stream>>>(
        hc_h, hc_l, wout_h, wout_l, b_out, nullptr, nullptr, nullptr, r_h, r_l, nullptr, nullptr, 1024, 512);
    // fused q/k/v projection: N=1536, BN=128, grid 792
    gemm_mfma_k<128, 12, 4, false><<<792, 256, 0, stream>>>(
        r_h, r_l, wqkv_h, wqkv_l, bqkv, nullptr, nullptr, nullptr, qkv_h, qkv_l, vt_h, vt_l, 512, QKV_N);
    // flash sliding-window attention
    swa_flash_k<<<dim3(TT / 64, NHH, BB), 256, 0, stream>>>(qkv_h, qkv_l, vt_h, vt_l, ob_h, ob_l);
    // out = (ob @ wo + bo)[t >= M]: N=512, BN=64, grid 528
    gemm_mfma_k<64, 8, 0, true><<<528, 256, 0, stream>>>(
        ob_h, ob_l, wo_h, wo_l, bo, nullptr, nullptr, out, nullptr, nullptr, nullptr, nullptr, 512, 512);
}

// Round 6
// 263.023 us; speedup vs baseline: 3.7424x; 1.0244x over previous
//
#include <hip/hip_runtime.h>
#include <math.h>
#include <stdint.h>

#define BB 2
#define SS 2048
#define DD 512
#define HH 1024
#define MMETA 64
#define KCONV 4
#define NHH 8
#define DHH 64
#define WINN 256
#define TT (MMETA + SS)     // 2112
#define BT (BB * TT)        // 4224
#define QKV_N 1536

typedef __attribute__((ext_vector_type(8))) short short8v;   // 8 bf16 = 4 VGPR
typedef __attribute__((ext_vector_type(4))) float f32x4;

__device__ __forceinline__ unsigned short f2bf(float f) {
    union { float f; unsigned u; } c; c.f = f;
    unsigned u = c.u;
    unsigned r = (u + 0x7fffu + ((u >> 16) & 1u)) >> 16;   // RNE
    return (unsigned short)r;
}
__device__ __forceinline__ float bf2f(unsigned short h) {
    union { unsigned u; float f; } c; c.u = ((unsigned)h) << 16;
    return c.f;
}

__device__ __forceinline__ void gload_lds16(const void* g, void* l) {
    __builtin_amdgcn_global_load_lds(
        (const __attribute__((address_space(1))) unsigned int*)g,
        (__attribute__((address_space(3))) unsigned int*)l, 16, 0, 0);
}

// ---------------------------------------------------------------------------
// mega weight transpose+split: all 9 weights in one dispatch
//   W [K][N] fp32 -> Wh/Wl [N][K] bf16
// ---------------------------------------------------------------------------
struct WJobs {
    const float* W[9];
    unsigned short* Wh[9];
    unsigned short* Wl[9];
    int K[9];
    int N[9];
    int base[10];    // tile-count prefix sum
};

__global__ __launch_bounds__(256) void wsplit_all_k(WJobs jb)
{
    __shared__ float tile[64][65];
    const int t = blockIdx.x;
    int j = 0;
    while (t >= jb.base[j + 1]) ++j;
    const int local = t - jb.base[j];
    const int K = jb.K[j], N = jb.N[j];
    const int nx = N >> 6;
    const int k0 = (local / nx) * 64, n0 = (local % nx) * 64;
    const float* W = jb.W[j];
    unsigned short* Wh = jb.Wh[j];
    unsigned short* Wl = jb.Wl[j];

    const int tid = threadIdx.x;
    #pragma unroll
    for (int i = 0; i < 16; ++i) {
        int lin = i * 256 + tid;
        int kr = lin >> 6, nc = lin & 63;
        tile[kr][nc] = W[(size_t)(k0 + kr) * N + n0 + nc];
    }
    __syncthreads();
    #pragma unroll
    for (int i = 0; i < 16; ++i) {
        int lin = i * 256 + tid;
        int nr = lin >> 6, kc = lin & 63;
        float v = tile[kc][nr];
        unsigned short hi = f2bf(v);
        size_t idx = (size_t)(n0 + nr) * K + k0 + kc;
        Wh[idx] = hi;
        Wl[idx] = f2bf(v - bf2f(hi));
    }
}

// ---------------------------------------------------------------------------
// concat q/k/v biases into one [1536] buffer
// ---------------------------------------------------------------------------
__global__ __launch_bounds__(256) void bias_concat_k(
    const float* __restrict__ bq, const float* __restrict__ bk,
    const float* __restrict__ bv, float* __restrict__ o)
{
    int i = blockIdx.x * 256 + threadIdx.x;
    if (i >= QKV_N) return;
    float v;
    if (i < 512) v = bq[i];
    else if (i < 1024) v = bk[i - 512];
    else v = bv[i - 1024];
    o[i] = v;
}

// ---------------------------------------------------------------------------
// build xm = concat(meta, x) -> hi/lo bf16 [BT][D]
// ---------------------------------------------------------------------------
__global__ __launch_bounds__(256) void build_xm_k(
    const float* __restrict__ x, const float* __restrict__ meta,
    unsigned short* __restrict__ xh, unsigned short* __restrict__ xl)
{
    int idx = blockIdx.x * 256 + threadIdx.x;   // float4 index over BT*128
    if (idx >= BT * 128) return;
    int row = idx >> 7, c4 = idx & 127;
    int b = row >= TT;
    int t = row - b * TT;
    float4 v = (t < MMETA) ? ((const float4*)(meta + (size_t)t * DD))[c4]
                           : ((const float4*)(x + ((size_t)b * SS + (t - MMETA)) * DD))[c4];
    ushort4 h, lo;
    h.x = f2bf(v.x); lo.x = f2bf(v.x - bf2f(h.x));
    h.y = f2bf(v.y); lo.y = f2bf(v.y - bf2f(h.y));
    h.z = f2bf(v.z); lo.z = f2bf(v.z - bf2f(h.z));
    h.w = f2bf(v.w); lo.w = f2bf(v.w - bf2f(h.w));
    ((ushort4*)xh)[idx] = h;
    ((ushort4*)xl)[idx] = lo;
}

// ---------------------------------------------------------------------------
// bf16x3 MFMA GEMM:  C = epi( A @ W^T + bias [, res] )
//   BM in {32,64}; BN=64; 1D grid of (BT/BM)*GN blocks, XCD-chunk swizzled.
//   EPI: 0 bias->fp32; 1 silu->hi/lo; 2 res+silu->hi/lo; 3 bias->hi/lo;
//        4 bias->hi/lo for cols<1024, transposed vt write for cols>=1024
// ---------------------------------------------------------------------------
template<int BM, int BN, int GN, int EPI, bool DROPMETA>
__global__ __launch_bounds__(256, 4) void gemm_mfma_k(
    const unsigned short* __restrict__ Ah, const unsigned short* __restrict__ Al,
    const unsigned short* __restrict__ Wh, const unsigned short* __restrict__ Wl,
    const float* __restrict__ bias,
    const unsigned short* __restrict__ resh, const unsigned short* __restrict__ resl,
    float* __restrict__ outf, unsigned short* __restrict__ outh,
    unsigned short* __restrict__ outl,
    unsigned short* __restrict__ vth, unsigned short* __restrict__ vtl,
    int K, int N)
{
    static_assert(BM == 32 || BM == 64, "");
    constexpr int MF = BM / 32;
    constexpr int NF = BN / 32;
    constexpr int ABYTES = BM * 64;    // BM rows x 32 k x 2B
    constexpr int BBYTES = BN * 64;
    constexpr int BUFB = 2 * ABYTES + 2 * BBYTES;
    __shared__ short8v smem_v[(2 * BUFB) / 16];
    char* smem = (char*)smem_v;

    // XCD-chunk swizzle (bijective since NWG % 8 == 0)
    constexpr int NWG = (BT / BM) * GN;
    const int orig = blockIdx.x;
    const int swz = (orig & 7) * (NWG >> 3) + (orig >> 3);
    const int row0 = (swz / GN) * BM;
    const int n0 = (swz % GN) * BN;

    const int tid = threadIdx.x;
    const int l = tid & 63, wid = tid >> 6;
    const int wm = wid >> 1, wn = wid & 1;
    const int lr = l & 15, lg = l >> 4;

    const char* Ahg0 = (const char*)Ah + (size_t)row0 * K * 2;
    const char* Alg0 = (const char*)Al + (size_t)row0 * K * 2;
    const char* Whg  = (const char*)Wh + (size_t)n0 * K * 2;
    const char* Wlg  = (const char*)Wl + (size_t)n0 * K * 2;

    // conflict-free swizzle: sigma(r) = (r>>1)&3 over the 4 16B segs of a row
    int a_off[MF], b_off[NF];
    #pragma unroll
    for (int mf = 0; mf < MF; ++mf) {
        int r = wm * (BM / 2) + mf * 16 + lr;
        a_off[mf] = r * 64 + ((lg * 16) ^ (((r >> 1) & 3) << 4));
    }
    #pragma unroll
    for (int nf = 0; nf < NF; ++nf) {
        int r = wn * (BN / 2) + nf * 16 + lr;
        b_off[nf] = r * 64 + ((lg * 16) ^ (((r >> 1) & 3) << 4));
    }

    f32x4 acc[MF][NF];
    #pragma unroll
    for (int mf = 0; mf < MF; ++mf)
        #pragma unroll
        for (int nf = 0; nf < NF; ++nf) acc[mf][nf] = (f32x4){0.f, 0.f, 0.f, 0.f};

    const int NT = K / 32;

    auto stage = [&](int buf, int t) {
        char* lb = smem + buf * BUFB;
        const size_t kb = (size_t)t * 64;
        if (tid * 16 < ABYTES) {
            int off = tid * 16;
            int row = off >> 6;
            int sc = (off & 63) ^ (((row >> 1) & 3) << 4);
            size_t gb = (size_t)row * (K * 2) + kb + sc;
            gload_lds16(Ahg0 + gb, lb + off);
            gload_lds16(Alg0 + gb, lb + ABYTES + off);
        }
        #pragma unroll
        for (int it = 0; it < BBYTES / 4096; ++it) {
            int off = (it * 256 + tid) * 16;
            int row = off >> 6;
            int sc = (off & 63) ^ (((row >> 1) & 3) << 4);
            size_t gb = (size_t)row * (K * 2) + kb + sc;
            gload_lds16(Whg + gb, lb + 2 * ABYTES + off);
            gload_lds16(Wlg + gb, lb + 2 * ABYTES + BBYTES + off);
        }
    };

    stage(0, 0);
    __syncthreads();

    int cur = 0;
    for (int t = 0; t < NT; ++t) {
        if (t + 1 < NT) stage(cur ^ 1, t + 1);
        char* lb = smem + cur * BUFB;
        short8v ah[MF], al[MF], bh[NF], bl[NF];
        #pragma unroll
        for (int mf = 0; mf < MF; ++mf) {
            ah[mf] = *(const short8v*)(lb + a_off[mf]);
            al[mf] = *(const short8v*)(lb + ABYTES + a_off[mf]);
        }
        #pragma unroll
        for (int nf = 0; nf < NF; ++nf) {
            bh[nf] = *(const short8v*)(lb + 2 * ABYTES + b_off[nf]);
            bl[nf] = *(const short8v*)(lb + 2 * ABYTES + BBYTES + b_off[nf]);
        }
        #pragma unroll
        for (int mf = 0; mf < MF; ++mf)
            #pragma unroll
            for (int nf = 0; nf < NF; ++nf) {
                acc[mf][nf] = __builtin_amdgcn_mfma_f32_16x16x32_bf16(ah[mf], bh[nf], acc[mf][nf], 0, 0, 0);
                acc[mf][nf] = __builtin_amdgcn_mfma_f32_16x16x32_bf16(ah[mf], bl[nf], acc[mf][nf], 0, 0, 0);
                acc[mf][nf] = __builtin_amdgcn_mfma_f32_16x16x32_bf16(al[mf], bh[nf], acc[mf][nf], 0, 0, 0);
            }
        __syncthreads();
        cur ^= 1;
    }

    // epilogue: C/D layout col = lane&15, row = (lane>>4)*4 + reg
    #pragma unroll
    for (int mf = 0; mf < MF; ++mf) {
        #pragma unroll
        for (int nf = 0; nf < NF; ++nf) {
            int col = n0 + wn * (BN / 2) + nf * 16 + lr;
            float bv = bias[col];
            if (EPI == 4 && col >= 1024) {
                // transposed v write: vt[d][token], 4 consecutive tokens packed
                unsigned short hv[4], lv[4];
                #pragma unroll
                for (int j = 0; j < 4; ++j) {
                    float v = acc[mf][nf][j] + bv;
                    unsigned short hi = f2bf(v);
                    hv[j] = hi; lv[j] = f2bf(v - bf2f(hi));
                }
                int dg = col - 1024;
                size_t tok = (size_t)row0 + wm * (BM / 2) + mf * 16 + lg * 4;
                *(ushort4*)(vth + (size_t)dg * BT + tok) = *(ushort4*)hv;
                *(ushort4*)(vtl + (size_t)dg * BT + tok) = *(ushort4*)lv;
            } else {
                #pragma unroll
                for (int j = 0; j < 4; ++j) {
                    int row = row0 + wm * (BM / 2) + mf * 16 + lg * 4 + j;
                    float v = acc[mf][nf][j] + bv;
                    if (EPI == 1 || EPI == 2) v = v / (1.f + __expf(-v));
                    size_t idx = (size_t)row * N + col;
                    if (EPI == 2) v += bf2f(resh[idx]) + bf2f(resl[idx]);
                    if (EPI == 0) {
                        if (DROPMETA) {
                            int b = row >= TT;
                            int t2 = row - b * TT;
                            if (t2 >= MMETA)
                                outf[((size_t)b * SS + (t2 - MMETA)) * N + col] = v;
                        } else {
                            outf[idx] = v;
                        }
                    } else {
                        unsigned short hi = f2bf(v);
                        outh[idx] = hi;
                        outl[idx] = f2bf(v - bf2f(hi));
                    }
                }
            }
        }
    }
}

// ---------------------------------------------------------------------------
// causal depthwise conv (K=4) + L2 normalize; out as hi/lo bf16
// ---------------------------------------------------------------------------
__global__ __launch_bounds__(256) void conv_norm_k(
    const float* __restrict__ qlin, const float* __restrict__ convw,
    unsigned short* __restrict__ qh, unsigned short* __restrict__ ql)
{
    const int row = blockIdx.x;
    const int b = row >= TT;
    const int t = row - b * TT;
    const int tid = threadIdx.x;

    float vals[2];
    float ss = 0.f;
    #pragma unroll
    for (int e = 0; e < 2; ++e) {
        int d = tid + e * 256;
        float acc = 0.f;
        #pragma unroll
        for (int k = 0; k < KCONV; ++k) {
            int tt = t - (KCONV - 1) + k;
            if (tt >= 0)
                acc += qlin[((size_t)b * TT + tt) * DD + d] * convw[k * DD + d];
        }
        vals[e] = acc;
        ss += acc * acc;
    }
    #pragma unroll
    for (int off = 32; off > 0; off >>= 1)
        ss += __shfl_xor(ss, off);
    __shared__ float red[4];
    if ((tid & 63) == 0) red[tid >> 6] = ss;
    __syncthreads();
    float total = red[0] + red[1] + red[2] + red[3];
    float inv = 1.f / fmaxf(sqrtf(total), 1e-12f);
    #pragma unroll
    for (int e = 0; e < 2; ++e) {
        int d = tid + e * 256;
        float v = vals[e] * inv;
        unsigned short hi = f2bf(v);
        qh[(size_t)row * DD + d] = hi;
        ql[(size_t)row * DD + d] = f2bf(v - bf2f(hi));
    }
}

// ---------------------------------------------------------------------------
// Flash sliding-window attention, MFMA, V^T staged from global.
//   Block: 64 queries x 1 head x 1 batch, 4 waves (wave = 16 query rows).
// ---------------------------------------------------------------------------
__global__ __launch_bounds__(256, 2) void swa_flash_k(
    const unsigned short* __restrict__ qkvh, const unsigned short* __restrict__ qkvl,
    const unsigned short* __restrict__ vth, const unsigned short* __restrict__ vtl,
    unsigned short* __restrict__ oh, unsigned short* __restrict__ ol)
{
    // LDS: Kh 8192 | Kl 8192 | Vh 8192 | Vl 8192 | P 4x2304
    __shared__ short8v lds_v[41984 / 16];
    char* lds = (char*)lds_v;
    char* Kh_lds = lds;
    char* Kl_lds = lds + 8192;
    char* Vh_lds = lds + 16384;
    char* Vl_lds = lds + 24576;
    char* P_lds  = lds + 32768;

    const int tid = threadIdx.x;
    const int lane = tid & 63, w = tid >> 6;
    const int l15 = lane & 15, lg = lane >> 4;
    const int q0 = blockIdx.x * 64;
    const int h = blockIdx.y, b = blockIdx.z;
    const int rowbase = b * TT;

    // Q fragments in registers (A-frag: row = lane&15, k = lg*8..+7)
    const int qrow = rowbase + q0 + w * 16 + l15;
    short8v qhf[2], qlf[2];
    #pragma unroll
    for (int kh = 0; kh < 2; ++kh) {
        size_t off = (size_t)qrow * QKV_N + h * 64 + kh * 32 + lg * 8;
        qhf[kh] = *(const short8v*)(qkvh + off);
        qlf[kh] = *(const short8v*)(qkvl + off);
    }

    f32x4 o_acc[4];
    #pragma unroll
    for (int td = 0; td < 4; ++td) o_acc[td] = (f32x4){0.f, 0.f, 0.f, 0.f};
    float m_r[4], l_r[4];
    #pragma unroll
    for (int r = 0; r < 4; ++r) { m_r[r] = -1e30f; l_r[r] = 0.f; }

    char* Pw = P_lds + w * 2304;   // per-wave [16][72] bf16

    for (int kt = 0; kt < 5; ++kt) {
        const int kst = q0 - 256 + kt * 64;
        if (kst + 64 <= 0) continue;    // staged tiles always have kst >= 0
        __syncthreads();
        // --- stage K rows (hi/lo): K[key][d], 128B rows, sigma = key&7 ---
        #pragma unroll
        for (int it = 0; it < 2; ++it) {
            int lin = it * 256 + tid;
            int r = lin >> 3, seg = lin & 7;
            int colb = (seg * 16) ^ ((r & 7) << 4);
            size_t gb = ((size_t)(rowbase + kst + r) * QKV_N + 512 + h * 64) * 2 + colb;
            gload_lds16((const char*)qkvh + gb, Kh_lds + lin * 16);
            gload_lds16((const char*)qkvl + gb, Kl_lds + lin * 16);
        }
        // --- stage V^T rows (hi/lo): vt[d][token], 128B rows, sigma = d&7 ---
        #pragma unroll
        for (int it = 0; it < 2; ++it) {
            int lin = it * 256 + tid;
            int dd = lin >> 3, seg = lin & 7;
            int colb = (seg * 16) ^ ((dd & 7) << 4);
            size_t gb = ((size_t)(h * 64 + dd) * BT + rowbase + kst) * 2 + colb;
            gload_lds16((const char*)vth + gb, Vh_lds + lin * 16);
            gload_lds16((const char*)vtl + gb, Vl_lds + lin * 16);
        }
        __syncthreads();

        // --- S = Q K^T (bf16x3) ---
        f32x4 s_fr[4];
        #pragma unroll
        for (int tj = 0; tj < 4; ++tj) s_fr[tj] = (f32x4){0.f, 0.f, 0.f, 0.f};
        #pragma unroll
        for (int tj = 0; tj < 4; ++tj) {
            int j = tj * 16 + l15;
            #pragma unroll
            for (int kh = 0; kh < 2; ++kh) {
                int colb = (kh * 64 + lg * 16) ^ ((j & 7) << 4);
                short8v kbh = *(const short8v*)(Kh_lds + j * 128 + colb);
                short8v kbl = *(const short8v*)(Kl_lds + j * 128 + colb);
                s_fr[tj] = __builtin_amdgcn_mfma_f32_16x16x32_bf16(qhf[kh], kbh, s_fr[tj], 0, 0, 0);
                s_fr[tj] = __builtin_amdgcn_mfma_f32_16x16x32_bf16(qhf[kh], kbl, s_fr[tj], 0, 0, 0);
                s_fr[tj] = __builtin_amdgcn_mfma_f32_16x16x32_bf16(qlf[kh], kbh, s_fr[tj], 0, 0, 0);
            }
        }
        // --- mask + scale ---
        #pragma unroll
        for (int tj = 0; tj < 4; ++tj) {
            int j = kst + tj * 16 + l15;
            #pragma unroll
            for (int r = 0; r < 4; ++r) {
                int i = q0 + w * 16 + lg * 4 + r;
                bool valid = (j <= i) && (i - j < WINN);
                s_fr[tj][r] = valid ? s_fr[tj][r] * 0.125f : -1e30f;
            }
        }
        // --- online softmax update ---
        float mx[4];
        #pragma unroll
        for (int r = 0; r < 4; ++r) {
            mx[r] = fmaxf(fmaxf(s_fr[0][r], s_fr[1][r]), fmaxf(s_fr[2][r], s_fr[3][r]));
            #pragma unroll
            for (int msk = 1; msk <= 8; msk <<= 1)
                mx[r] = fmaxf(mx[r], __shfl_xor(mx[r], msk));
            float mn = fmaxf(m_r[r], mx[r]);
            float sc = __expf(m_r[r] - mn);
            m_r[r] = mn;
            l_r[r] *= sc;
            #pragma unroll
            for (int td = 0; td < 4; ++td) o_acc[td][r] *= sc;
        }
        float rs[4] = {0.f, 0.f, 0.f, 0.f};
        #pragma unroll
        for (int tj = 0; tj < 4; ++tj) {
            #pragma unroll
            for (int r = 0; r < 4; ++r) {
                float p = __expf(s_fr[tj][r] - m_r[r]);
                rs[r] += p;
                ((unsigned short*)Pw)[(lg * 4 + r) * 72 + tj * 16 + l15] = f2bf(p);
            }
        }
        #pragma unroll
        for (int r = 0; r < 4; ++r) {
            #pragma unroll
            for (int msk = 1; msk <= 8; msk <<= 1)
                rs[r] += __shfl_xor(rs[r], msk);
            l_r[r] += rs[r];
        }
        // --- PV: O += P @ V  (P bf16 from LDS, V^T hi/lo from LDS) ---
        short8v pa[2];
        #pragma unroll
        for (int jh = 0; jh < 2; ++jh)
            pa[jh] = *(const short8v*)(Pw + l15 * 144 + jh * 64 + lg * 16);
        #pragma unroll
        for (int td = 0; td < 4; ++td) {
            int drow = td * 16 + l15;
            #pragma unroll
            for (int jh = 0; jh < 2; ++jh) {
                int colb = (jh * 64 + lg * 16) ^ ((drow & 7) << 4);
                short8v vfh = *(const short8v*)(Vh_lds + drow * 128 + colb);
                short8v vfl = *(const short8v*)(Vl_lds + drow * 128 + colb);
                o_acc[td] = __builtin_amdgcn_mfma_f32_16x16x32_bf16(pa[jh], vfh, o_acc[td], 0, 0, 0);
                o_acc[td] = __builtin_amdgcn_mfma_f32_16x16x32_bf16(pa[jh], vfl, o_acc[td], 0, 0, 0);
            }
        }
    }

    // --- epilogue ---
    #pragma unroll
    for (int r = 0; r < 4; ++r) {
        float inv = 1.f / l_r[r];
        int row = rowbase + q0 + w * 16 + lg * 4 + r;
        #pragma unroll
        for (int td = 0; td < 4; ++td) {
            float v = o_acc[td][r] * inv;
            size_t idx = (size_t)row * DD + h * 64 + td * 16 + l15;
            unsigned short hi = f2bf(v);
            oh[idx] = hi;
            ol[idx] = f2bf(v - bf2f(hi));
        }
    }
}

// ---------------------------------------------------------------------------
// Launch
// ---------------------------------------------------------------------------
extern "C" void kernel_launch(void* const* d_in, const int* in_sizes, int n_in,
                              void* d_out, int out_size, void* d_ws, size_t ws_size,
                              hipStream_t stream)
{
    const float* x       = (const float*)d_in[0];
    const float* meta    = (const float*)d_in[1];
    const float* qp_w    = (const float*)d_in[2];
    const float* qp_b    = (const float*)d_in[3];
    const float* qp_conv = (const float*)d_in[4];
    const float* w_in    = (const float*)d_in[5];
    const float* b_in    = (const float*)d_in[6];
    const float* w_hid   = (const float*)d_in[7];
    const float* b_hid   = (const float*)d_in[8];
    const float* w_out   = (const float*)d_in[9];
    const float* b_out   = (const float*)d_in[10];
    const float* wq      = (const float*)d_in[11];
    const float* bq      = (const float*)d_in[12];
    const float* wk      = (const float*)d_in[13];
    const float* bk      = (const float*)d_in[14];
    const float* wv      = (const float*)d_in[15];
    const float* bv      = (const float*)d_in[16];
    const float* wo      = (const float*)d_in[17];
    const float* bo      = (const float*)d_in[18];
    float* out = (float*)d_out;

    typedef unsigned short us;
    char* p = (char*)d_ws;
    auto alloc = [&](size_t n) { char* r = p; p += (n + 255) & ~(size_t)255; return r; };

    // split weights (hi/lo, transposed [N][K])
    us* wqp_h   = (us*)alloc(512 * 512 * 2);   us* wqp_l   = (us*)alloc(512 * 512 * 2);
    us* win_h   = (us*)alloc(512 * 1024 * 2);  us* win_l   = (us*)alloc(512 * 1024 * 2);
    us* whid0_h = (us*)alloc(1024 * 1024 * 2); us* whid0_l = (us*)alloc(1024 * 1024 * 2);
    us* whid1_h = (us*)alloc(1024 * 1024 * 2); us* whid1_l = (us*)alloc(1024 * 1024 * 2);
    us* wout_h  = (us*)alloc(1024 * 512 * 2);  us* wout_l  = (us*)alloc(1024 * 512 * 2);
    us* wqkv_h  = (us*)alloc((size_t)QKV_N * 512 * 2);
    us* wqkv_l  = (us*)alloc((size_t)QKV_N * 512 * 2);
    us* wo_h    = (us*)alloc(512 * 512 * 2);   us* wo_l    = (us*)alloc(512 * 512 * 2);
    float* bqkv = (float*)alloc(QKV_N * 4);

    const size_t HALF = (size_t)BT * 512 * 2;   // 4.3 MB
    char* RA = alloc(2 * HALF);   // xm hi/lo  -> later ob hi/lo
    char* RB = alloc(2 * HALF);   // qlin fp32
    char* RC = alloc(2 * HALF);   // qn hi/lo -> r hi/lo
    char* RD = alloc(6 * HALF);   // ha hi/lo -> hc hi/lo -> qkv hi/lo (q,k only)
    char* RE = alloc(4 * HALF);   // hb hi/lo -> vt hi/lo ([512][BT] each)

    us* xm_h = (us*)RA;   us* xm_l = (us*)(RA + HALF);
    float* qlin = (float*)RB;
    us* qn_h = (us*)RC;   us* qn_l = (us*)(RC + HALF);
    us* ha_h = (us*)RD;   us* ha_l = (us*)(RD + 2 * HALF);
    us* hb_h = (us*)RE;   us* hb_l = (us*)(RE + 2 * HALF);
    us* hc_h = ha_h;      us* hc_l = ha_l;
    us* r_h  = qn_h;      us* r_l  = qn_l;
    us* qkv_h = (us*)RD;  us* qkv_l = (us*)(RD + 3 * HALF);
    us* vt_h  = (us*)RE;  us* vt_l  = (us*)(RE + HALF);
    us* ob_h = (us*)RA;   us* ob_l = (us*)(RA + HALF);

    // --- weight prep: one mega dispatch ---
    WJobs jb;
    const float* Ws[9]   = {qp_w, w_in, w_hid, w_hid + (size_t)1024 * 1024, w_out,
                            wq, wk, wv, wo};
    us* Whs[9] = {wqp_h, win_h, whid0_h, whid1_h, wout_h,
                  wqkv_h, wqkv_h + 512 * 512, wqkv_h + 2 * 512 * 512, wo_h};
    us* Wls[9] = {wqp_l, win_l, whid0_l, whid1_l, wout_l,
                  wqkv_l, wqkv_l + 512 * 512, wqkv_l + 2 * 512 * 512, wo_l};
    int Ks[9] = {512, 512, 1024, 1024, 1024, 512, 512, 512, 512};
    int Ns[9] = {512, 1024, 1024, 1024, 512, 512, 512, 512, 512};
    int acc_t = 0;
    for (int j = 0; j < 9; ++j) {
        jb.W[j] = Ws[j]; jb.Wh[j] = Whs[j]; jb.Wl[j] = Wls[j];
        jb.K[j] = Ks[j]; jb.N[j] = Ns[j];
        jb.base[j] = acc_t;
        acc_t += (Ks[j] / 64) * (Ns[j] / 64);
    }
    jb.base[9] = acc_t;    // 1088
    wsplit_all_k<<<acc_t, 256, 0, stream>>>(jb);
    bias_concat_k<<<6, 256, 0, stream>>>(bq, bk, bv, bqkv);

    // --- pipeline ---
    build_xm_k<<<(BT * 128 + 255) / 256, 256, 0, stream>>>(x, meta, xm_h, xm_l);

    // qlin = xm @ qp_w + b (fp32 out): N=512, BM=32, grid 1056
    gemm_mfma_k<32, 64, 8, 0, false><<<1056, 256, 0, stream>>>(
        xm_h, xm_l, wqp_h, wqp_l, qp_b, nullptr, nullptr, qlin, nullptr, nullptr, nullptr, nullptr, 512, 512);
    conv_norm_k<<<BT, 256, 0, stream>>>(qlin, qp_conv, qn_h, qn_l);
    // ha = silu(qn @ w_in + b_in): N=1024, grid 1056
    gemm_mfma_k<64, 64, 16, 1, false><<<1056, 256, 0, stream>>>(
        qn_h, qn_l, win_h, win_l, b_in, nullptr, nullptr, nullptr, ha_h, ha_l, nullptr, nullptr, 512, 1024);
    gemm_mfma_k<64, 64, 16, 2, false><<<1056, 256, 0, stream>>>(
        ha_h, ha_l, whid0_h, whid0_l, b_hid, ha_h, ha_l, nullptr, hb_h, hb_l, nullptr, nullptr, 1024, 1024);
    gemm_mfma_k<64, 64, 16, 2, false><<<1056, 256, 0, stream>>>(
        hb_h, hb_l, whid1_h, whid1_l, b_hid + HH, hb_h, hb_l, nullptr, hc_h, hc_l, nullptr, nullptr, 1024, 1024);
    // r = silu(hc @ w_out + b_out): N=512, BM=32, grid 1056
    gemm_mfma_k<32, 64, 8, 1, false><<<1056, 256, 0, stream>>>(
        hc_h, hc_l, wout_h, wout_l, b_out, nullptr, nullptr, nullptr, r_h, r_l, nullptr, nullptr, 1024, 512);
    // fused q/k/v projection: N=1536, grid 1584
    gemm_mfma_k<64, 64, 24, 4, false><<<1584, 256, 0, stream>>>(
        r_h, r_l, wqkv_h, wqkv_l, bqkv, nullptr, nullptr, nullptr, qkv_h, qkv_l, vt_h, vt_l, 512, QKV_N);
    // flash sliding-window attention
    swa_flash_k<<<dim3(TT / 64, NHH, BB), 256, 0, stream>>>(qkv_h, qkv_l, vt_h, vt_l, ob_h, ob_l);
    // out = (ob @ wo + bo)[t >= M]: N=512, BM=32, grid 1056
    gemm_mfma_k<32, 64, 8, 0, true><<<1056, 256, 0, stream>>>(
        ob_h, ob_l, wo_h, wo_l, bo, nullptr, nullptr, out, nullptr, nullptr, nullptr, nullptr, 512, 512);
}

// Round 7
// 254.152 us; speedup vs baseline: 3.8730x; 1.0349x over previous
//
#include <hip/hip_runtime.h>
#include <math.h>
#include <stdint.h>

#define BB 2
#define SS 2048
#define DD 512
#define HH 1024
#define MMETA 64
#define KCONV 4
#define NHH 8
#define DHH 64
#define WINN 256
#define TT (MMETA + SS)     // 2112
#define BT (BB * TT)        // 4224
#define QKV_N 1536

typedef __attribute__((ext_vector_type(8))) short short8v;   // 8 bf16 = 4 VGPR
typedef __attribute__((ext_vector_type(4))) float f32x4;

__device__ __forceinline__ unsigned short f2bf(float f) {
    union { float f; unsigned u; } c; c.f = f;
    unsigned u = c.u;
    unsigned r = (u + 0x7fffu + ((u >> 16) & 1u)) >> 16;   // RNE
    return (unsigned short)r;
}
__device__ __forceinline__ float bf2f(unsigned short h) {
    union { unsigned u; float f; } c; c.u = ((unsigned)h) << 16;
    return c.f;
}

__device__ __forceinline__ void gload_lds16(const void* g, void* l) {
    __builtin_amdgcn_global_load_lds(
        (const __attribute__((address_space(1))) unsigned int*)g,
        (__attribute__((address_space(3))) unsigned int*)l, 16, 0, 0);
}

// counted vmcnt wait (T4): wait until at most N of this thread's VMEM ops remain
template<int N>
__device__ __forceinline__ void vm_wait() {
    if constexpr (N == 0)      asm volatile("s_waitcnt vmcnt(0)" ::: "memory");
    else if constexpr (N == 4) asm volatile("s_waitcnt vmcnt(4)" ::: "memory");
    else if constexpr (N == 6) asm volatile("s_waitcnt vmcnt(6)" ::: "memory");
    else static_assert(N == 0, "unsupported vmcnt");
}

// ---------------------------------------------------------------------------
// mega weight transpose+split: all 9 weights in one dispatch
// ---------------------------------------------------------------------------
struct WJobs {
    const float* W[9];
    unsigned short* Wh[9];
    unsigned short* Wl[9];
    int K[9];
    int N[9];
    int base[10];    // tile-count prefix sum
};

__global__ __launch_bounds__(256) void wsplit_all_k(WJobs jb)
{
    __shared__ float tile[64][65];
    const int t = blockIdx.x;
    int j = 0;
    while (t >= jb.base[j + 1]) ++j;
    const int local = t - jb.base[j];
    const int K = jb.K[j], N = jb.N[j];
    const int nx = N >> 6;
    const int k0 = (local / nx) * 64, n0 = (local % nx) * 64;
    const float* W = jb.W[j];
    unsigned short* Wh = jb.Wh[j];
    unsigned short* Wl = jb.Wl[j];

    const int tid = threadIdx.x;
    #pragma unroll
    for (int i = 0; i < 16; ++i) {
        int lin = i * 256 + tid;
        int kr = lin >> 6, nc = lin & 63;
        tile[kr][nc] = W[(size_t)(k0 + kr) * N + n0 + nc];
    }
    __syncthreads();
    #pragma unroll
    for (int i = 0; i < 16; ++i) {
        int lin = i * 256 + tid;
        int nr = lin >> 6, kc = lin & 63;
        float v = tile[kc][nr];
        unsigned short hi = f2bf(v);
        size_t idx = (size_t)(n0 + nr) * K + k0 + kc;
        Wh[idx] = hi;
        Wl[idx] = f2bf(v - bf2f(hi));
    }
}

// ---------------------------------------------------------------------------
__global__ __launch_bounds__(256) void bias_concat_k(
    const float* __restrict__ bq, const float* __restrict__ bk,
    const float* __restrict__ bv, float* __restrict__ o)
{
    int i = blockIdx.x * 256 + threadIdx.x;
    if (i >= QKV_N) return;
    float v;
    if (i < 512) v = bq[i];
    else if (i < 1024) v = bk[i - 512];
    else v = bv[i - 1024];
    o[i] = v;
}

// ---------------------------------------------------------------------------
__global__ __launch_bounds__(256) void build_xm_k(
    const float* __restrict__ x, const float* __restrict__ meta,
    unsigned short* __restrict__ xh, unsigned short* __restrict__ xl)
{
    int idx = blockIdx.x * 256 + threadIdx.x;   // float4 index over BT*128
    if (idx >= BT * 128) return;
    int row = idx >> 7, c4 = idx & 127;
    int b = row >= TT;
    int t = row - b * TT;
    float4 v = (t < MMETA) ? ((const float4*)(meta + (size_t)t * DD))[c4]
                           : ((const float4*)(x + ((size_t)b * SS + (t - MMETA)) * DD))[c4];
    ushort4 h, lo;
    h.x = f2bf(v.x); lo.x = f2bf(v.x - bf2f(h.x));
    h.y = f2bf(v.y); lo.y = f2bf(v.y - bf2f(h.y));
    h.z = f2bf(v.z); lo.z = f2bf(v.z - bf2f(h.z));
    h.w = f2bf(v.w); lo.w = f2bf(v.w - bf2f(h.w));
    ((ushort4*)xh)[idx] = h;
    ((ushort4*)xl)[idx] = lo;
}

// ---------------------------------------------------------------------------
// bf16x3 MFMA GEMM with counted-vmcnt double-buffer pipeline (T4).
//   BM=64; BN in {64,128}; 1D grid of 66*GN blocks, XCD-chunk swizzled.
//   EPI: 0 bias->fp32; 1 silu->hi/lo; 2 res+silu->hi/lo;
//        4 bias->hi/lo for cols<1024, transposed vt write for cols>=1024
// ---------------------------------------------------------------------------
template<int BN, int GN, int EPI, bool DROPMETA>
__global__ __launch_bounds__(256, 3) void gemm_mfma_k(
    const unsigned short* __restrict__ Ah, const unsigned short* __restrict__ Al,
    const unsigned short* __restrict__ Wh, const unsigned short* __restrict__ Wl,
    const float* __restrict__ bias,
    const unsigned short* __restrict__ resh, const unsigned short* __restrict__ resl,
    float* __restrict__ outf, unsigned short* __restrict__ outh,
    unsigned short* __restrict__ outl,
    unsigned short* __restrict__ vth, unsigned short* __restrict__ vtl,
    int K, int N)
{
    constexpr int BM = 64;
    constexpr int MF = 2;              // wave covers 32 rows
    constexpr int NF = BN / 32;        // wave covers BN/2 cols
    constexpr int ABYTES = BM * 64;    // 4 KB per stream
    constexpr int BBYTES = BN * 64;
    constexpr int BUFB = 2 * ABYTES + 2 * BBYTES;
    constexpr int LOADS = 2 + (BN / 64) * 2;   // per-thread loads per stage
    __shared__ short8v smem_v[(2 * BUFB) / 16];
    char* smem = (char*)smem_v;

    // XCD-chunk swizzle (bijective since NWG % 8 == 0)
    constexpr int NWG = 66 * GN;
    const int orig = blockIdx.x;
    const int swz = (orig & 7) * (NWG >> 3) + (orig >> 3);
    const int row0 = (swz / GN) * BM;
    const int n0 = (swz % GN) * BN;

    const int tid = threadIdx.x;
    const int l = tid & 63, wid = tid >> 6;
    const int wm = wid >> 1, wn = wid & 1;
    const int lr = l & 15, lg = l >> 4;

    const char* Ahg0 = (const char*)Ah + (size_t)row0 * K * 2;
    const char* Alg0 = (const char*)Al + (size_t)row0 * K * 2;
    const char* Whg  = (const char*)Wh + (size_t)n0 * K * 2;
    const char* Wlg  = (const char*)Wl + (size_t)n0 * K * 2;

    // conflict-free swizzle: sigma(r) = (r>>1)&3 over the 4 16B segs of a row
    int a_off[MF], b_off[NF];
    #pragma unroll
    for (int mf = 0; mf < MF; ++mf) {
        int r = wm * 32 + mf * 16 + lr;
        a_off[mf] = r * 64 + ((lg * 16) ^ (((r >> 1) & 3) << 4));
    }
    #pragma unroll
    for (int nf = 0; nf < NF; ++nf) {
        int r = wn * (BN / 2) + nf * 16 + lr;
        b_off[nf] = r * 64 + ((lg * 16) ^ (((r >> 1) & 3) << 4));
    }

    f32x4 acc[MF][NF];
    #pragma unroll
    for (int mf = 0; mf < MF; ++mf)
        #pragma unroll
        for (int nf = 0; nf < NF; ++nf) acc[mf][nf] = (f32x4){0.f, 0.f, 0.f, 0.f};

    const int NT = K / 32;

    auto stage = [&](int buf, int t) {
        char* lb = smem + buf * BUFB;
        const size_t kb = (size_t)t * 64;
        {
            int off = tid * 16;
            int row = off >> 6;
            int sc = (off & 63) ^ (((row >> 1) & 3) << 4);
            size_t gb = (size_t)row * (K * 2) + kb + sc;
            gload_lds16(Ahg0 + gb, lb + off);
            gload_lds16(Alg0 + gb, lb + ABYTES + off);
        }
        #pragma unroll
        for (int it = 0; it < BBYTES / 4096; ++it) {
            int off = (it * 256 + tid) * 16;
            int row = off >> 6;
            int sc = (off & 63) ^ (((row >> 1) & 3) << 4);
            size_t gb = (size_t)row * (K * 2) + kb + sc;
            gload_lds16(Whg + gb, lb + 2 * ABYTES + off);
            gload_lds16(Wlg + gb, lb + 2 * ABYTES + BBYTES + off);
        }
    };

    stage(0, 0);

    int cur = 0;
    for (int t = 0; t < NT; ++t) {
        if (t + 1 < NT) {
            stage(cur ^ 1, t + 1);
            vm_wait<LOADS>();        // wait only for tile t's loads; t+1 stays in flight
        } else {
            vm_wait<0>();
        }
        __builtin_amdgcn_s_barrier();
        __builtin_amdgcn_sched_barrier(0);

        char* lb = smem + cur * BUFB;
        short8v ah[MF], al[MF], bh[NF], bl[NF];
        #pragma unroll
        for (int mf = 0; mf < MF; ++mf) {
            ah[mf] = *(const short8v*)(lb + a_off[mf]);
            al[mf] = *(const short8v*)(lb + ABYTES + a_off[mf]);
        }
        #pragma unroll
        for (int nf = 0; nf < NF; ++nf) {
            bh[nf] = *(const short8v*)(lb + 2 * ABYTES + b_off[nf]);
            bl[nf] = *(const short8v*)(lb + 2 * ABYTES + BBYTES + b_off[nf]);
        }
        __builtin_amdgcn_s_setprio(1);
        #pragma unroll
        for (int mf = 0; mf < MF; ++mf)
            #pragma unroll
            for (int nf = 0; nf < NF; ++nf) {
                acc[mf][nf] = __builtin_amdgcn_mfma_f32_16x16x32_bf16(ah[mf], bh[nf], acc[mf][nf], 0, 0, 0);
                acc[mf][nf] = __builtin_amdgcn_mfma_f32_16x16x32_bf16(ah[mf], bl[nf], acc[mf][nf], 0, 0, 0);
                acc[mf][nf] = __builtin_amdgcn_mfma_f32_16x16x32_bf16(al[mf], bh[nf], acc[mf][nf], 0, 0, 0);
            }
        __builtin_amdgcn_s_setprio(0);
        __builtin_amdgcn_s_barrier();    // all reads of buf[cur] done before overwrite
        cur ^= 1;
    }

    // epilogue: C/D layout col = lane&15, row = (lane>>4)*4 + reg
    #pragma unroll
    for (int mf = 0; mf < MF; ++mf) {
        #pragma unroll
        for (int nf = 0; nf < NF; ++nf) {
            int col = n0 + wn * (BN / 2) + nf * 16 + lr;
            float bv = bias[col];
            if (EPI == 4 && col >= 1024) {
                unsigned short hv[4], lv[4];
                #pragma unroll
                for (int j = 0; j < 4; ++j) {
                    float v = acc[mf][nf][j] + bv;
                    unsigned short hi = f2bf(v);
                    hv[j] = hi; lv[j] = f2bf(v - bf2f(hi));
                }
                int dg = col - 1024;
                size_t tok = (size_t)row0 + wm * 32 + mf * 16 + lg * 4;
                *(ushort4*)(vth + (size_t)dg * BT + tok) = *(ushort4*)hv;
                *(ushort4*)(vtl + (size_t)dg * BT + tok) = *(ushort4*)lv;
            } else {
                #pragma unroll
                for (int j = 0; j < 4; ++j) {
                    int row = row0 + wm * 32 + mf * 16 + lg * 4 + j;
                    float v = acc[mf][nf][j] + bv;
                    if (EPI == 1 || EPI == 2) v = v / (1.f + __expf(-v));
                    size_t idx = (size_t)row * N + col;
                    if (EPI == 2) v += bf2f(resh[idx]) + bf2f(resl[idx]);
                    if (EPI == 0) {
                        if (DROPMETA) {
                            int b = row >= TT;
                            int t2 = row - b * TT;
                            if (t2 >= MMETA)
                                outf[((size_t)b * SS + (t2 - MMETA)) * N + col] = v;
                        } else {
                            outf[idx] = v;
                        }
                    } else {
                        unsigned short hi = f2bf(v);
                        outh[idx] = hi;
                        outl[idx] = f2bf(v - bf2f(hi));
                    }
                }
            }
        }
    }
}

// ---------------------------------------------------------------------------
__global__ __launch_bounds__(256) void conv_norm_k(
    const float* __restrict__ qlin, const float* __restrict__ convw,
    unsigned short* __restrict__ qh, unsigned short* __restrict__ ql)
{
    const int row = blockIdx.x;
    const int b = row >= TT;
    const int t = row - b * TT;
    const int tid = threadIdx.x;

    float vals[2];
    float ss = 0.f;
    #pragma unroll
    for (int e = 0; e < 2; ++e) {
        int d = tid + e * 256;
        float acc = 0.f;
        #pragma unroll
        for (int k = 0; k < KCONV; ++k) {
            int tt = t - (KCONV - 1) + k;
            if (tt >= 0)
                acc += qlin[((size_t)b * TT + tt) * DD + d] * convw[k * DD + d];
        }
        vals[e] = acc;
        ss += acc * acc;
    }
    #pragma unroll
    for (int off = 32; off > 0; off >>= 1)
        ss += __shfl_xor(ss, off);
    __shared__ float red[4];
    if ((tid & 63) == 0) red[tid >> 6] = ss;
    __syncthreads();
    float total = red[0] + red[1] + red[2] + red[3];
    float inv = 1.f / fmaxf(sqrtf(total), 1e-12f);
    #pragma unroll
    for (int e = 0; e < 2; ++e) {
        int d = tid + e * 256;
        float v = vals[e] * inv;
        unsigned short hi = f2bf(v);
        qh[(size_t)row * DD + d] = hi;
        ql[(size_t)row * DD + d] = f2bf(v - bf2f(hi));
    }
}

// ---------------------------------------------------------------------------
// Flash sliding-window attention, MFMA, V^T staged from global.
// ---------------------------------------------------------------------------
__global__ __launch_bounds__(256, 2) void swa_flash_k(
    const unsigned short* __restrict__ qkvh, const unsigned short* __restrict__ qkvl,
    const unsigned short* __restrict__ vth, const unsigned short* __restrict__ vtl,
    unsigned short* __restrict__ oh, unsigned short* __restrict__ ol)
{
    // LDS: Kh 8192 | Kl 8192 | Vh 8192 | Vl 8192 | P 4x2304
    __shared__ short8v lds_v[41984 / 16];
    char* lds = (char*)lds_v;
    char* Kh_lds = lds;
    char* Kl_lds = lds + 8192;
    char* Vh_lds = lds + 16384;
    char* Vl_lds = lds + 24576;
    char* P_lds  = lds + 32768;

    const int tid = threadIdx.x;
    const int lane = tid & 63, w = tid >> 6;
    const int l15 = lane & 15, lg = lane >> 4;
    const int q0 = blockIdx.x * 64;
    const int h = blockIdx.y, b = blockIdx.z;
    const int rowbase = b * TT;

    const int qrow = rowbase + q0 + w * 16 + l15;
    short8v qhf[2], qlf[2];
    #pragma unroll
    for (int kh = 0; kh < 2; ++kh) {
        size_t off = (size_t)qrow * QKV_N + h * 64 + kh * 32 + lg * 8;
        qhf[kh] = *(const short8v*)(qkvh + off);
        qlf[kh] = *(const short8v*)(qkvl + off);
    }

    f32x4 o_acc[4];
    #pragma unroll
    for (int td = 0; td < 4; ++td) o_acc[td] = (f32x4){0.f, 0.f, 0.f, 0.f};
    float m_r[4], l_r[4];
    #pragma unroll
    for (int r = 0; r < 4; ++r) { m_r[r] = -1e30f; l_r[r] = 0.f; }

    char* Pw = P_lds + w * 2304;   // per-wave [16][72] bf16

    for (int kt = 0; kt < 5; ++kt) {
        const int kst = q0 - 256 + kt * 64;
        if (kst + 64 <= 0) continue;
        __syncthreads();
        #pragma unroll
        for (int it = 0; it < 2; ++it) {
            int lin = it * 256 + tid;
            int r = lin >> 3, seg = lin & 7;
            int colb = (seg * 16) ^ ((r & 7) << 4);
            size_t gb = ((size_t)(rowbase + kst + r) * QKV_N + 512 + h * 64) * 2 + colb;
            gload_lds16((const char*)qkvh + gb, Kh_lds + lin * 16);
            gload_lds16((const char*)qkvl + gb, Kl_lds + lin * 16);
        }
        #pragma unroll
        for (int it = 0; it < 2; ++it) {
            int lin = it * 256 + tid;
            int dd = lin >> 3, seg = lin & 7;
            int colb = (seg * 16) ^ ((dd & 7) << 4);
            size_t gb = ((size_t)(h * 64 + dd) * BT + rowbase + kst) * 2 + colb;
            gload_lds16((const char*)vth + gb, Vh_lds + lin * 16);
            gload_lds16((const char*)vtl + gb, Vl_lds + lin * 16);
        }
        __syncthreads();

        f32x4 s_fr[4];
        #pragma unroll
        for (int tj = 0; tj < 4; ++tj) s_fr[tj] = (f32x4){0.f, 0.f, 0.f, 0.f};
        #pragma unroll
        for (int tj = 0; tj < 4; ++tj) {
            int j = tj * 16 + l15;
            #pragma unroll
            for (int kh = 0; kh < 2; ++kh) {
                int colb = (kh * 64 + lg * 16) ^ ((j & 7) << 4);
                short8v kbh = *(const short8v*)(Kh_lds + j * 128 + colb);
                short8v kbl = *(const short8v*)(Kl_lds + j * 128 + colb);
                s_fr[tj] = __builtin_amdgcn_mfma_f32_16x16x32_bf16(qhf[kh], kbh, s_fr[tj], 0, 0, 0);
                s_fr[tj] = __builtin_amdgcn_mfma_f32_16x16x32_bf16(qhf[kh], kbl, s_fr[tj], 0, 0, 0);
                s_fr[tj] = __builtin_amdgcn_mfma_f32_16x16x32_bf16(qlf[kh], kbh, s_fr[tj], 0, 0, 0);
            }
        }
        #pragma unroll
        for (int tj = 0; tj < 4; ++tj) {
            int j = kst + tj * 16 + l15;
            #pragma unroll
            for (int r = 0; r < 4; ++r) {
                int i = q0 + w * 16 + lg * 4 + r;
                bool valid = (j <= i) && (i - j < WINN);
                s_fr[tj][r] = valid ? s_fr[tj][r] * 0.125f : -1e30f;
            }
        }
        float mx[4];
        #pragma unroll
        for (int r = 0; r < 4; ++r) {
            mx[r] = fmaxf(fmaxf(s_fr[0][r], s_fr[1][r]), fmaxf(s_fr[2][r], s_fr[3][r]));
            #pragma unroll
            for (int msk = 1; msk <= 8; msk <<= 1)
                mx[r] = fmaxf(mx[r], __shfl_xor(mx[r], msk));
            float mn = fmaxf(m_r[r], mx[r]);
            float sc = __expf(m_r[r] - mn);
            m_r[r] = mn;
            l_r[r] *= sc;
            #pragma unroll
            for (int td = 0; td < 4; ++td) o_acc[td][r] *= sc;
        }
        float rs[4] = {0.f, 0.f, 0.f, 0.f};
        #pragma unroll
        for (int tj = 0; tj < 4; ++tj) {
            #pragma unroll
            for (int r = 0; r < 4; ++r) {
                float p = __expf(s_fr[tj][r] - m_r[r]);
                rs[r] += p;
                ((unsigned short*)Pw)[(lg * 4 + r) * 72 + tj * 16 + l15] = f2bf(p);
            }
        }
        #pragma unroll
        for (int r = 0; r < 4; ++r) {
            #pragma unroll
            for (int msk = 1; msk <= 8; msk <<= 1)
                rs[r] += __shfl_xor(rs[r], msk);
            l_r[r] += rs[r];
        }
        short8v pa[2];
        #pragma unroll
        for (int jh = 0; jh < 2; ++jh)
            pa[jh] = *(const short8v*)(Pw + l15 * 144 + jh * 64 + lg * 16);
        #pragma unroll
        for (int td = 0; td < 4; ++td) {
            int drow = td * 16 + l15;
            #pragma unroll
            for (int jh = 0; jh < 2; ++jh) {
                int colb = (jh * 64 + lg * 16) ^ ((drow & 7) << 4);
                short8v vfh = *(const short8v*)(Vh_lds + drow * 128 + colb);
                short8v vfl = *(const short8v*)(Vl_lds + drow * 128 + colb);
                o_acc[td] = __builtin_amdgcn_mfma_f32_16x16x32_bf16(pa[jh], vfh, o_acc[td], 0, 0, 0);
                o_acc[td] = __builtin_amdgcn_mfma_f32_16x16x32_bf16(pa[jh], vfl, o_acc[td], 0, 0, 0);
            }
        }
    }

    #pragma unroll
    for (int r = 0; r < 4; ++r) {
        float inv = 1.f / l_r[r];
        int row = rowbase + q0 + w * 16 + lg * 4 + r;
        #pragma unroll
        for (int td = 0; td < 4; ++td) {
            float v = o_acc[td][r] * inv;
            size_t idx = (size_t)row * DD + h * 64 + td * 16 + l15;
            unsigned short hi = f2bf(v);
            oh[idx] = hi;
            ol[idx] = f2bf(v - bf2f(hi));
        }
    }
}

// ---------------------------------------------------------------------------
// Launch
// ---------------------------------------------------------------------------
extern "C" void kernel_launch(void* const* d_in, const int* in_sizes, int n_in,
                              void* d_out, int out_size, void* d_ws, size_t ws_size,
                              hipStream_t stream)
{
    const float* x       = (const float*)d_in[0];
    const float* meta    = (const float*)d_in[1];
    const float* qp_w    = (const float*)d_in[2];
    const float* qp_b    = (const float*)d_in[3];
    const float* qp_conv = (const float*)d_in[4];
    const float* w_in    = (const float*)d_in[5];
    const float* b_in    = (const float*)d_in[6];
    const float* w_hid   = (const float*)d_in[7];
    const float* b_hid   = (const float*)d_in[8];
    const float* w_out   = (const float*)d_in[9];
    const float* b_out   = (const float*)d_in[10];
    const float* wq      = (const float*)d_in[11];
    const float* bq      = (const float*)d_in[12];
    const float* wk      = (const float*)d_in[13];
    const float* bk      = (const float*)d_in[14];
    const float* wv      = (const float*)d_in[15];
    const float* bv      = (const float*)d_in[16];
    const float* wo      = (const float*)d_in[17];
    const float* bo      = (const float*)d_in[18];
    float* out = (float*)d_out;

    typedef unsigned short us;
    char* p = (char*)d_ws;
    auto alloc = [&](size_t n) { char* r = p; p += (n + 255) & ~(size_t)255; return r; };

    us* wqp_h   = (us*)alloc(512 * 512 * 2);   us* wqp_l   = (us*)alloc(512 * 512 * 2);
    us* win_h   = (us*)alloc(512 * 1024 * 2);  us* win_l   = (us*)alloc(512 * 1024 * 2);
    us* whid0_h = (us*)alloc(1024 * 1024 * 2); us* whid0_l = (us*)alloc(1024 * 1024 * 2);
    us* whid1_h = (us*)alloc(1024 * 1024 * 2); us* whid1_l = (us*)alloc(1024 * 1024 * 2);
    us* wout_h  = (us*)alloc(1024 * 512 * 2);  us* wout_l  = (us*)alloc(1024 * 512 * 2);
    us* wqkv_h  = (us*)alloc((size_t)QKV_N * 512 * 2);
    us* wqkv_l  = (us*)alloc((size_t)QKV_N * 512 * 2);
    us* wo_h    = (us*)alloc(512 * 512 * 2);   us* wo_l    = (us*)alloc(512 * 512 * 2);
    float* bqkv = (float*)alloc(QKV_N * 4);

    const size_t HALF = (size_t)BT * 512 * 2;   // 4.3 MB
    char* RA = alloc(2 * HALF);   // xm hi/lo  -> later ob hi/lo
    char* RB = alloc(2 * HALF);   // qlin fp32
    char* RC = alloc(2 * HALF);   // qn hi/lo -> r hi/lo
    char* RD = alloc(6 * HALF);   // ha hi/lo -> hc hi/lo -> qkv hi/lo (q,k only)
    char* RE = alloc(4 * HALF);   // hb hi/lo -> vt hi/lo ([512][BT] each)

    us* xm_h = (us*)RA;   us* xm_l = (us*)(RA + HALF);
    float* qlin = (float*)RB;
    us* qn_h = (us*)RC;   us* qn_l = (us*)(RC + HALF);
    us* ha_h = (us*)RD;   us* ha_l = (us*)(RD + 2 * HALF);
    us* hb_h = (us*)RE;   us* hb_l = (us*)(RE + 2 * HALF);
    us* hc_h = ha_h;      us* hc_l = ha_l;
    us* r_h  = qn_h;      us* r_l  = qn_l;
    us* qkv_h = (us*)RD;  us* qkv_l = (us*)(RD + 3 * HALF);
    us* vt_h  = (us*)RE;  us* vt_l  = (us*)(RE + HALF);
    us* ob_h = (us*)RA;   us* ob_l = (us*)(RA + HALF);

    // --- weight prep: one mega dispatch ---
    WJobs jb;
    const float* Ws[9]   = {qp_w, w_in, w_hid, w_hid + (size_t)1024 * 1024, w_out,
                            wq, wk, wv, wo};
    us* Whs[9] = {wqp_h, win_h, whid0_h, whid1_h, wout_h,
                  wqkv_h, wqkv_h + 512 * 512, wqkv_h + 2 * 512 * 512, wo_h};
    us* Wls[9] = {wqp_l, win_l, whid0_l, whid1_l, wout_l,
                  wqkv_l, wqkv_l + 512 * 512, wqkv_l + 2 * 512 * 512, wo_l};
    int Ks[9] = {512, 512, 1024, 1024, 1024, 512, 512, 512, 512};
    int Ns[9] = {512, 1024, 1024, 1024, 512, 512, 512, 512, 512};
    int acc_t = 0;
    for (int j = 0; j < 9; ++j) {
        jb.W[j] = Ws[j]; jb.Wh[j] = Whs[j]; jb.Wl[j] = Wls[j];
        jb.K[j] = Ks[j]; jb.N[j] = Ns[j];
        jb.base[j] = acc_t;
        acc_t += (Ks[j] / 64) * (Ns[j] / 64);
    }
    jb.base[9] = acc_t;    // 1088
    wsplit_all_k<<<acc_t, 256, 0, stream>>>(jb);
    bias_concat_k<<<6, 256, 0, stream>>>(bq, bk, bv, bqkv);

    // --- pipeline ---
    build_xm_k<<<(BT * 128 + 255) / 256, 256, 0, stream>>>(x, meta, xm_h, xm_l);

    // qlin = xm @ qp_w + b (fp32 out): N=512, BN=64, grid 528
    gemm_mfma_k<64, 8, 0, false><<<528, 256, 0, stream>>>(
        xm_h, xm_l, wqp_h, wqp_l, qp_b, nullptr, nullptr, qlin, nullptr, nullptr, nullptr, nullptr, 512, 512);
    conv_norm_k<<<BT, 256, 0, stream>>>(qlin, qp_conv, qn_h, qn_l);
    // ha = silu(qn @ w_in + b_in): N=1024, BN=128, grid 528
    gemm_mfma_k<128, 8, 1, false><<<528, 256, 0, stream>>>(
        qn_h, qn_l, win_h, win_l, b_in, nullptr, nullptr, nullptr, ha_h, ha_l, nullptr, nullptr, 512, 1024);
    gemm_mfma_k<128, 8, 2, false><<<528, 256, 0, stream>>>(
        ha_h, ha_l, whid0_h, whid0_l, b_hid, ha_h, ha_l, nullptr, hb_h, hb_l, nullptr, nullptr, 1024, 1024);
    gemm_mfma_k<128, 8, 2, false><<<528, 256, 0, stream>>>(
        hb_h, hb_l, whid1_h, whid1_l, b_hid + HH, hb_h, hb_l, nullptr, hc_h, hc_l, nullptr, nullptr, 1024, 1024);
    // r = silu(hc @ w_out + b_out): N=512, BN=64, grid 528
    gemm_mfma_k<64, 8, 1, false><<<528, 256, 0, stream>>>(
        hc_h, hc_l, wout_h, wout_l, b_out, nullptr, nullptr, nullptr, r_h, r_l, nullptr, nullptr, 1024, 512);
    // fused q/k/v projection: N=1536, BN=128, grid 792
    gemm_mfma_k<128, 12, 4, false><<<792, 256, 0, stream>>>(
        r_h, r_l, wqkv_h, wqkv_l, bqkv, nullptr, nullptr, nullptr, qkv_h, qkv_l, vt_h, vt_l, 512, QKV_N);
    // flash sliding-window attention
    swa_flash_k<<<dim3(TT / 64, NHH, BB), 256, 0, stream>>>(qkv_h, qkv_l, vt_h, vt_l, ob_h, ob_l);
    // out = (ob @ wo + bo)[t >= M]: N=512, BN=64, grid 528
    gemm_mfma_k<64, 8, 0, true><<<528, 256, 0, stream>>>(
        ob_h, ob_l, wo_h, wo_l, bo, nullptr, nullptr, out, nullptr, nullptr, nullptr, nullptr, 512, 512);
}